// Round 7
// baseline (344.623 us; speedup 1.0000x reference)
//
#include <hip/hip_runtime.h>
#include <hip/hip_bf16.h>

// MHA forward: B=4, S=1024, D=1024, H=16, DK=64
// outputs: out [4,1024,1024] f32, attn [4,16,1024,1024] f32 (concat in d_out)
//
// Packed operand layouts for the fused kernel (all bf16):
//   qhp/khp: [bh][half=dk/32][s][32]   -> frag loads 1KB contiguous
//   vp:      [bh][kb=s/32][dk][32]     -> PV frag loads 1KB contiguous

typedef __bf16 bf16_t;
typedef __bf16 bf16x4 __attribute__((ext_vector_type(4)));
typedef __bf16 bf16x8 __attribute__((ext_vector_type(8)));
typedef float f32x4 __attribute__((ext_vector_type(4)));

#define MFMA16(a, b, c) __builtin_amdgcn_mfma_f32_16x16x32_bf16(a, b, c, 0, 0, 0)

// ---------------------------------------------------------------- cast x -> bf16
__global__ __launch_bounds__(256) void cast_f32_bf16(const float* __restrict__ in,
                                                     bf16_t* __restrict__ out, int n4) {
    int i = blockIdx.x * blockDim.x + threadIdx.x;
    if (i >= n4) return;
    float4 v = reinterpret_cast<const float4*>(in)[i];
    bf16x4 o = { (bf16_t)v.x, (bf16_t)v.y, (bf16_t)v.z, (bf16_t)v.w };
    reinterpret_cast<bf16x4*>(out)[i] = o;
}

// ------------------------------------------- transpose + cast the 4 weight matrices
__global__ __launch_bounds__(1024) void transpose_cast_w(const float* __restrict__ w0,
                                                         const float* __restrict__ w1,
                                                         const float* __restrict__ w2,
                                                         const float* __restrict__ w3,
                                                         bf16_t* __restrict__ wt) {
    __shared__ float tile[32][33];
    const float* src = (blockIdx.z == 0) ? w0 : (blockIdx.z == 1) ? w1
                     : (blockIdx.z == 2) ? w2 : w3;
    bf16_t* dst = wt + (size_t)blockIdx.z * 1024 * 1024;
    int r0 = blockIdx.y * 32, c0 = blockIdx.x * 32;
    tile[threadIdx.y][threadIdx.x] = src[(size_t)(r0 + threadIdx.y) * 1024 + c0 + threadIdx.x];
    __syncthreads();
    dst[(size_t)(c0 + threadIdx.y) * 1024 + r0 + threadIdx.x] = (bf16_t)tile[threadIdx.x][threadIdx.y];
}

// ------------------------------------------------------- GEMM core (128x128 tile)
// block = 256 threads = 4 waves (2x2), each wave 64x64 output (4x4 frags)
#define GEMM_BODY(A, BT)                                                                 \
    __shared__ bf16_t As[128 * 32];                                                      \
    __shared__ bf16_t Bs[128 * 32];                                                      \
    const int tid = threadIdx.x;                                                         \
    const int lane = tid & 63, wave = tid >> 6;                                          \
    const int lr = lane & 15, lg = lane >> 4;                                            \
    const int m_base = blockIdx.x * 128, n_base = blockIdx.y * 128;                      \
    const int wm = (wave >> 1) * 64, wn = (wave & 1) * 64;                               \
    const int srow = tid >> 1;                                                           \
    const int sl0 = (tid & 1) * 2;                                                       \
    const int sl1 = sl0 + 1;                                                             \
    const int off0 = srow * 32 + ((sl0 ^ ((srow >> 1) & 3)) * 8);                        \
    const int off1 = srow * 32 + ((sl1 ^ ((srow >> 1) & 3)) * 8);                        \
    const bf16_t* aptr = (A) + (size_t)(m_base + srow) * 1024 + sl0 * 8;                 \
    const bf16_t* bptr = (BT) + (size_t)(n_base + srow) * 1024 + sl0 * 8;                \
    bf16x8 ra0 = *reinterpret_cast<const bf16x8*>(aptr);                                 \
    bf16x8 ra1 = *reinterpret_cast<const bf16x8*>(aptr + 8);                             \
    bf16x8 rb0 = *reinterpret_cast<const bf16x8*>(bptr);                                 \
    bf16x8 rb1 = *reinterpret_cast<const bf16x8*>(bptr + 8);                             \
    f32x4 acc[4][4] = {};                                                                \
    for (int kb = 32; kb <= 1024; kb += 32) {                                            \
        __syncthreads();                                                                 \
        *reinterpret_cast<bf16x8*>(&As[off0]) = ra0;                                     \
        *reinterpret_cast<bf16x8*>(&As[off1]) = ra1;                                     \
        *reinterpret_cast<bf16x8*>(&Bs[off0]) = rb0;                                     \
        *reinterpret_cast<bf16x8*>(&Bs[off1]) = rb1;                                     \
        if (kb < 1024) {                                                                 \
            ra0 = *reinterpret_cast<const bf16x8*>(aptr + kb);                           \
            ra1 = *reinterpret_cast<const bf16x8*>(aptr + kb + 8);                       \
            rb0 = *reinterpret_cast<const bf16x8*>(bptr + kb);                           \
            rb1 = *reinterpret_cast<const bf16x8*>(bptr + kb + 8);                       \
        }                                                                                \
        __syncthreads();                                                                 \
        bf16x8 af[4], bfr[4];                                                            \
        _Pragma("unroll") for (int i = 0; i < 4; ++i) {                                  \
            const int row = wm + i * 16 + lr;                                            \
            af[i] = *reinterpret_cast<const bf16x8*>(                                    \
                &As[row * 32 + ((lg ^ ((row >> 1) & 3)) * 8)]);                          \
        }                                                                                \
        _Pragma("unroll") for (int j = 0; j < 4; ++j) {                                  \
            const int row = wn + j * 16 + lr;                                            \
            bfr[j] = *reinterpret_cast<const bf16x8*>(                                   \
                &Bs[row * 32 + ((lg ^ ((row >> 1) & 3)) * 8)]);                          \
        }                                                                                \
        _Pragma("unroll") for (int i = 0; i < 4; ++i)                                    \
            _Pragma("unroll") for (int j = 0; j < 4; ++j)                                \
                acc[i][j] = MFMA16(af[i], bfr[j], acc[i][j]);                            \
    }

// ---------------------------------------------------- QKV projections, one launch
// blockIdx.z: 0 = Q -> qhp (x0.125), 1 = K -> khp, 2 = V -> vp
__global__ __launch_bounds__(256, 3) void gemm_qkv(const bf16_t* __restrict__ A,
                                                   const bf16_t* __restrict__ wT,
                                                   bf16_t* __restrict__ qhp,
                                                   bf16_t* __restrict__ khp,
                                                   bf16_t* __restrict__ vp) {
    const int z = blockIdx.z;
    const bf16_t* BT = wT + ((size_t)z << 20);
    GEMM_BODY(A, BT)
    bf16_t* dst = (z == 0) ? qhp : (z == 1) ? khp : vp;
    const float scale = (z == 0) ? 0.125f : 1.0f;
#pragma unroll
    for (int i = 0; i < 4; ++i)
#pragma unroll
        for (int j = 0; j < 4; ++j)
#pragma unroll
            for (int r = 0; r < 4; ++r) {
                const int row = m_base + wm + i * 16 + lg * 4 + r;
                const int col = n_base + wn + j * 16 + lr;
                const float v = acc[i][j][r] * scale;
                const int b = row >> 10, s = row & 1023;
                const int h = col >> 6, d = col & 63;
                const size_t bh16 = (size_t)(b * 16 + h) << 16;
                if (z == 2)   // vp[bh][s/32][d][s%32]
                    dst[bh16 + ((s >> 5) << 11) + d * 32 + (s & 31)] = (bf16_t)v;
                else          // qhp/khp[bh][d/32][s][d%32]
                    dst[bh16 + ((d >> 5) << 15) + s * 32 + (d & 31)] = (bf16_t)v;
            }
}

// ------------------------------------------------------------- output projection
__global__ __launch_bounds__(256, 3) void gemm_out(const bf16_t* __restrict__ A,
                                                   const bf16_t* __restrict__ BT,
                                                   float* __restrict__ out) {
    GEMM_BODY(A, BT)
#pragma unroll
    for (int i = 0; i < 4; ++i)
#pragma unroll
        for (int j = 0; j < 4; ++j)
#pragma unroll
            for (int r = 0; r < 4; ++r) {
                const int row = m_base + wm + i * 16 + lg * 4 + r;
                const int col = n_base + wn + j * 16 + lr;
                out[(size_t)row * 1024 + col] = acc[i][j][r];
            }
}

// --------------------------------------- fused scores+bias+softmax+attn-write+PV
// K-AMORTIZED: block = 64 q-rows (4 q-tiles) of one (b,h). K fragments for the
// wave's 256-col slice are loaded ONCE into kf[32] (128 VGPRs) and reused by 4
// sequential q-tile iterations. V re-read per q-tile from L2 (batched, 2 halves).
// Swapped QK^T: lane owns one q-row; softmax in-lane + 2 shuffles + tiny LDS.
__global__ __launch_bounds__(256, 2) void fused_attn(const bf16_t* __restrict__ qhp,
                                                     const bf16_t* __restrict__ khp,
                                                     const bf16_t* __restrict__ vp,
                                                     const float* __restrict__ bias,
                                                     float* __restrict__ attn,
                                                     bf16_t* __restrict__ ctxb) {
    __shared__ bf16_t plds[4][16][256];     // 32768 B: per-wave 16x256 P tile
    const int lane = threadIdx.x & 63;
    const int wave = threadIdx.x >> 6;
    const int lr = lane & 15, lg = lane >> 4;

    // decode 1024 blocks: g&7 = xcd slot; per-xcd: b fastest, then qt64, then h-ext
    const int g = blockIdx.x;
    const int j = g >> 3;                   // 0..127
    const int h = (g & 7) + 8 * (j >> 6);   // 0..15
    const int qt = (j >> 2) & 15;           // 64-row q-tile index
    const int b = j & 3;
    const int bh = b * 16 + h;
    const int m_base = qt * 64;

    const int c0 = wave * 256;              // this wave's k-col slice
    const bf16_t* kp0 = khp + ((size_t)bh << 16) + (size_t)(c0 + lr) * 32 + lg * 8;
    const bf16_t* qbase = qhp + ((size_t)bh << 16);
    const bf16_t* vpb = vp + ((size_t)bh << 16) + (size_t)(wave * 8) * 2048 + lr * 32 + lg * 8;

    // ---- K loads ONCE (32 x b128 = 128 VGPRs, reused by all 4 q-tiles)
    bf16x8 kf0[16], kf1[16];
#pragma unroll
    for (int f = 0; f < 16; ++f) {
        kf0[f] = *reinterpret_cast<const bf16x8*>(kp0 + f * 512);
        kf1[f] = *reinterpret_cast<const bf16x8*>(kp0 + 32768 + f * 512);
    }

    float* smaxp = reinterpret_cast<float*>(&plds[0][0][0]);   // 64 f32 (aliased)
    float* ssump = smaxp + 64;                                 // 64 f32 (aliased)
    char* pw = reinterpret_cast<char*>(&plds[wave][0][0]);
    const int swz = (lr & 7) << 4;

    for (int qi = 0; qi < 4; ++qi) {
        const int m0 = m_base + qi * 16;

        // Q B-frag for this q-tile
        const bf16x8 aq0 = *reinterpret_cast<const bf16x8*>(qbase + (m0 + lr) * 32 + lg * 8);
        const bf16x8 aq1 = *reinterpret_cast<const bf16x8*>(qbase + 32768 + (m0 + lr) * 32 + lg * 8);

        // ---- QK^T (swapped): acc[f][r] = S[q=m0+lr][k=c0+f*16+lg*4+r]
        f32x4 acc[16];
#pragma unroll
        for (int f = 0; f < 16; ++f) {
            const f32x4 z4 = {0.f, 0.f, 0.f, 0.f};
            acc[f] = MFMA16(kf0[f], aq0, z4);
            acc[f] = MFMA16(kf1[f], aq1, acc[f]);
        }
        // ---- bias (16 x f32x4, offsets immediate)
        const float* brow = bias + ((size_t)h << 20) + (size_t)(m0 + lr) * 1024 + c0 + lg * 4;
#pragma unroll
        for (int f = 0; f < 16; ++f) {
            f32x4 bv = *reinterpret_cast<const f32x4*>(brow + f * 16);
            acc[f] += bv;
        }

        // ---- row max: in-lane over 64, shuffle xor16/32, LDS cross-wave
        f32x4 m4 = acc[0];
#pragma unroll
        for (int f = 1; f < 16; ++f) {
#pragma unroll
            for (int r = 0; r < 4; ++r) m4[r] = fmaxf(m4[r], acc[f][r]);
        }
        float mx = fmaxf(fmaxf(m4[0], m4[1]), fmaxf(m4[2], m4[3]));
        mx = fmaxf(mx, __shfl_xor(mx, 16));
        mx = fmaxf(mx, __shfl_xor(mx, 32));
        if (lane < 16) smaxp[wave * 16 + lr] = mx;
        __syncthreads();
        const float gm = fmaxf(fmaxf(smaxp[lr], smaxp[16 + lr]),
                               fmaxf(smaxp[32 + lr], smaxp[48 + lr]));

        // ---- exp once + row sum
        f32x4 s4 = {0.f, 0.f, 0.f, 0.f};
#pragma unroll
        for (int f = 0; f < 16; ++f) {
#pragma unroll
            for (int r = 0; r < 4; ++r) {
                const float e = __expf(acc[f][r] - gm);
                acc[f][r] = e;
                s4[r] += e;
            }
        }
        float sm = (s4[0] + s4[1]) + (s4[2] + s4[3]);
        sm += __shfl_xor(sm, 16);
        sm += __shfl_xor(sm, 32);
        if (lane < 16) ssump[wave * 16 + lr] = sm;
        __syncthreads();
        const float invl = 1.0f / (ssump[lr] + ssump[16 + lr] + ssump[32 + lr] + ssump[48 + lr]);
        __syncthreads();   // guard: smax/ssum alias the P region written below

        // ---- write normalized attn (f32x4, offsets immediate) + pack P to LDS
        float* orow = attn + ((size_t)bh << 20) + (size_t)(m0 + lr) * 1024 + c0 + lg * 4;
#pragma unroll
        for (int f = 0; f < 16; ++f) {
            f32x4 v = acc[f];
#pragma unroll
            for (int r = 0; r < 4; ++r) v[r] *= invl;
            *reinterpret_cast<f32x4*>(orow + f * 16) = v;
            bf16x4 pb = { (bf16_t)v[0], (bf16_t)v[1], (bf16_t)v[2], (bf16_t)v[3] };
            *reinterpret_cast<bf16x4*>(pw + lr * 512 + ((f * 32 + lg * 8) ^ swz)) = pb;
        }
        // (no barrier: plds[wave] written and read only by this wave)

        // ---- PV: A = P (LDS), B = V in 2 reg-batched halves (L2-hot re-read)
        f32x4 cacc[4];
#pragma unroll
        for (int f2 = 0; f2 < 4; ++f2) cacc[f2] = (f32x4){0.f, 0.f, 0.f, 0.f};
#pragma unroll
        for (int half = 0; half < 2; ++half) {
            bf16x8 vf[4][4];
#pragma unroll
            for (int k2 = 0; k2 < 4; ++k2)
#pragma unroll
                for (int f2 = 0; f2 < 4; ++f2)
                    vf[k2][f2] = *reinterpret_cast<const bf16x8*>(
                        vpb + (half * 4 + k2) * 2048 + f2 * 512);
#pragma unroll
            for (int k2 = 0; k2 < 4; ++k2) {
                const int ks = half * 4 + k2;
                bf16x8 pa = *reinterpret_cast<const bf16x8*>(
                    pw + lr * 512 + ((ks * 64 + lg * 16) ^ swz));
#pragma unroll
                for (int f2 = 0; f2 < 4; ++f2)
                    cacc[f2] = MFMA16(pa, vf[k2][f2], cacc[f2]);
            }
        }
        __syncthreads();   // all waves done with P tiles; re-alias as cred

        // ---- cross-wave ctx reduce via LDS (aliases plds)
        float* cred = reinterpret_cast<float*>(&plds[0][0][0]);    // [4][16][64] f32
#pragma unroll
        for (int f2 = 0; f2 < 4; ++f2)
#pragma unroll
            for (int r = 0; r < 4; ++r)
                cred[wave * 1024 + (lg * 4 + r) * 64 + f2 * 16 + lr] = cacc[f2][r];
        __syncthreads();
        const int row_l = wave * 4 + lg;
        const int dk0 = lr * 4;
        f32x4 s0 = *reinterpret_cast<const f32x4*>(&cred[0 * 1024 + row_l * 64 + dk0]);
        f32x4 s1 = *reinterpret_cast<const f32x4*>(&cred[1 * 1024 + row_l * 64 + dk0]);
        f32x4 s2 = *reinterpret_cast<const f32x4*>(&cred[2 * 1024 + row_l * 64 + dk0]);
        f32x4 s3 = *reinterpret_cast<const f32x4*>(&cred[3 * 1024 + row_l * 64 + dk0]);
        f32x4 st = (s0 + s1) + (s2 + s3);
        bf16x4 o4 = { (bf16_t)st[0], (bf16_t)st[1], (bf16_t)st[2], (bf16_t)st[3] };
        *reinterpret_cast<bf16x4*>(
            &ctxb[(size_t)(b * 1024 + m0 + row_l) * 1024 + h * 64 + dk0]) = o4;
        __syncthreads();   // cred reads done before next iteration's smax writes
    }
}

// ---------------------------------------------------------------------- launcher
extern "C" void kernel_launch(void* const* d_in, const int* in_sizes, int n_in,
                              void* d_out, int out_size, void* d_ws, size_t ws_size,
                              hipStream_t stream) {
    const float* x    = (const float*)d_in[0];
    const float* bias = (const float*)d_in[1];
    const float* Wq   = (const float*)d_in[2];
    const float* Wk   = (const float*)d_in[3];
    const float* Wv   = (const float*)d_in[4];
    const float* Wo   = (const float*)d_in[5];
    float* out  = (float*)d_out;
    float* attn = out + (size_t)4 * 1024 * 1024;

    char* ws = (char*)d_ws;
    bf16_t* xb   = (bf16_t*)(ws);                      //  8 MB [4096,1024]
    bf16_t* wT   = (bf16_t*)(ws + ((size_t)8 << 20));  //  8 MB 4x [1024,1024] transposed
    bf16_t* qhp  = (bf16_t*)(ws + ((size_t)16 << 20)); //  8 MB Q/8 packed half-planes
    bf16_t* khp  = (bf16_t*)(ws + ((size_t)24 << 20)); //  8 MB K packed half-planes
    bf16_t* vp   = (bf16_t*)(ws + ((size_t)32 << 20)); //  8 MB V packed k-tiles
    bf16_t* ctxb = (bf16_t*)(ws + ((size_t)40 << 20)); //  8 MB ctx [B,S,D]
    bf16_t* woT = wT + ((size_t)3 << 20);

    cast_f32_bf16<<<dim3(4096), dim3(256), 0, stream>>>(x, xb, 1024 * 1024);
    transpose_cast_w<<<dim3(32, 32, 4), dim3(32, 32), 0, stream>>>(Wq, Wk, Wv, Wo, wT);

    gemm_qkv<<<dim3(32, 8, 3), dim3(256), 0, stream>>>(xb, wT, qhp, khp, vp);

    fused_attn<<<dim3(1024), dim3(256), 0, stream>>>(qhp, khp, vp, bias, attn, ctxb);

    gemm_out<<<dim3(32, 8), dim3(256), 0, stream>>>(ctxb, woT, out);
}

// Round 8
// 218.631 us; speedup vs baseline: 1.5763x; 1.5763x over previous
//
#include <hip/hip_runtime.h>
#include <hip/hip_bf16.h>

// MHA forward: B=4, S=1024, D=1024, H=16, DK=64
// outputs: out [4,1024,1024] f32, attn [4,16,1024,1024] f32 (concat in d_out)
//
// Packed operand layouts for the fused kernel (all bf16):
//   qhp/khp: [bh][half=dk/32][s][32]   -> frag loads 1KB contiguous
//   vp:      [bh][kb=s/32][dk][32]     -> PV frag loads 1KB contiguous

typedef __bf16 bf16_t;
typedef __bf16 bf16x4 __attribute__((ext_vector_type(4)));
typedef __bf16 bf16x8 __attribute__((ext_vector_type(8)));
typedef float f32x4 __attribute__((ext_vector_type(4)));

#define MFMA16(a, b, c) __builtin_amdgcn_mfma_f32_16x16x32_bf16(a, b, c, 0, 0, 0)

// ---------------------------------------------------------------- cast x -> bf16
__global__ __launch_bounds__(256) void cast_f32_bf16(const float* __restrict__ in,
                                                     bf16_t* __restrict__ out, int n4) {
    int i = blockIdx.x * blockDim.x + threadIdx.x;
    if (i >= n4) return;
    float4 v = reinterpret_cast<const float4*>(in)[i];
    bf16x4 o = { (bf16_t)v.x, (bf16_t)v.y, (bf16_t)v.z, (bf16_t)v.w };
    reinterpret_cast<bf16x4*>(out)[i] = o;
}

// ------------------------------------------- transpose + cast the 4 weight matrices
__global__ __launch_bounds__(1024) void transpose_cast_w(const float* __restrict__ w0,
                                                         const float* __restrict__ w1,
                                                         const float* __restrict__ w2,
                                                         const float* __restrict__ w3,
                                                         bf16_t* __restrict__ wt) {
    __shared__ float tile[32][33];
    const float* src = (blockIdx.z == 0) ? w0 : (blockIdx.z == 1) ? w1
                     : (blockIdx.z == 2) ? w2 : w3;
    bf16_t* dst = wt + (size_t)blockIdx.z * 1024 * 1024;
    int r0 = blockIdx.y * 32, c0 = blockIdx.x * 32;
    tile[threadIdx.y][threadIdx.x] = src[(size_t)(r0 + threadIdx.y) * 1024 + c0 + threadIdx.x];
    __syncthreads();
    dst[(size_t)(c0 + threadIdx.y) * 1024 + r0 + threadIdx.x] = (bf16_t)tile[threadIdx.x][threadIdx.y];
}

// ------------------------------------------------------- GEMM core (128x128 tile)
// block = 256 threads = 4 waves (2x2), each wave 64x64 output (4x4 frags)
#define GEMM_BODY(A, BT)                                                                 \
    __shared__ bf16_t As[128 * 32];                                                      \
    __shared__ bf16_t Bs[128 * 32];                                                      \
    const int tid = threadIdx.x;                                                         \
    const int lane = tid & 63, wave = tid >> 6;                                          \
    const int lr = lane & 15, lg = lane >> 4;                                            \
    const int m_base = blockIdx.x * 128, n_base = blockIdx.y * 128;                      \
    const int wm = (wave >> 1) * 64, wn = (wave & 1) * 64;                               \
    const int srow = tid >> 1;                                                           \
    const int sl0 = (tid & 1) * 2;                                                       \
    const int sl1 = sl0 + 1;                                                             \
    const int off0 = srow * 32 + ((sl0 ^ ((srow >> 1) & 3)) * 8);                        \
    const int off1 = srow * 32 + ((sl1 ^ ((srow >> 1) & 3)) * 8);                        \
    const bf16_t* aptr = (A) + (size_t)(m_base + srow) * 1024 + sl0 * 8;                 \
    const bf16_t* bptr = (BT) + (size_t)(n_base + srow) * 1024 + sl0 * 8;                \
    bf16x8 ra0 = *reinterpret_cast<const bf16x8*>(aptr);                                 \
    bf16x8 ra1 = *reinterpret_cast<const bf16x8*>(aptr + 8);                             \
    bf16x8 rb0 = *reinterpret_cast<const bf16x8*>(bptr);                                 \
    bf16x8 rb1 = *reinterpret_cast<const bf16x8*>(bptr + 8);                             \
    f32x4 acc[4][4] = {};                                                                \
    for (int kb = 32; kb <= 1024; kb += 32) {                                            \
        __syncthreads();                                                                 \
        *reinterpret_cast<bf16x8*>(&As[off0]) = ra0;                                     \
        *reinterpret_cast<bf16x8*>(&As[off1]) = ra1;                                     \
        *reinterpret_cast<bf16x8*>(&Bs[off0]) = rb0;                                     \
        *reinterpret_cast<bf16x8*>(&Bs[off1]) = rb1;                                     \
        if (kb < 1024) {                                                                 \
            ra0 = *reinterpret_cast<const bf16x8*>(aptr + kb);                           \
            ra1 = *reinterpret_cast<const bf16x8*>(aptr + kb + 8);                       \
            rb0 = *reinterpret_cast<const bf16x8*>(bptr + kb);                           \
            rb1 = *reinterpret_cast<const bf16x8*>(bptr + kb + 8);                       \
        }                                                                                \
        __syncthreads();                                                                 \
        bf16x8 af[4], bfr[4];                                                            \
        _Pragma("unroll") for (int i = 0; i < 4; ++i) {                                  \
            const int row = wm + i * 16 + lr;                                            \
            af[i] = *reinterpret_cast<const bf16x8*>(                                    \
                &As[row * 32 + ((lg ^ ((row >> 1) & 3)) * 8)]);                          \
        }                                                                                \
        _Pragma("unroll") for (int j = 0; j < 4; ++j) {                                  \
            const int row = wn + j * 16 + lr;                                            \
            bfr[j] = *reinterpret_cast<const bf16x8*>(                                   \
                &Bs[row * 32 + ((lg ^ ((row >> 1) & 3)) * 8)]);                          \
        }                                                                                \
        _Pragma("unroll") for (int i = 0; i < 4; ++i)                                    \
            _Pragma("unroll") for (int j = 0; j < 4; ++j)                                \
                acc[i][j] = MFMA16(af[i], bfr[j], acc[i][j]);                            \
    }

// ---------------------------------------------------- QKV projections, one launch
// blockIdx.z: 0 = Q -> qhp (x0.125), 1 = K -> khp, 2 = V -> vp
__global__ __launch_bounds__(256, 3) void gemm_qkv(const bf16_t* __restrict__ A,
                                                   const bf16_t* __restrict__ wT,
                                                   bf16_t* __restrict__ qhp,
                                                   bf16_t* __restrict__ khp,
                                                   bf16_t* __restrict__ vp) {
    const int z = blockIdx.z;
    const bf16_t* BT = wT + ((size_t)z << 20);
    GEMM_BODY(A, BT)
    bf16_t* dst = (z == 0) ? qhp : (z == 1) ? khp : vp;
    const float scale = (z == 0) ? 0.125f : 1.0f;
#pragma unroll
    for (int i = 0; i < 4; ++i)
#pragma unroll
        for (int j = 0; j < 4; ++j)
#pragma unroll
            for (int r = 0; r < 4; ++r) {
                const int row = m_base + wm + i * 16 + lg * 4 + r;
                const int col = n_base + wn + j * 16 + lr;
                const float v = acc[i][j][r] * scale;
                const int b = row >> 10, s = row & 1023;
                const int h = col >> 6, d = col & 63;
                const size_t bh16 = (size_t)(b * 16 + h) << 16;
                if (z == 2)   // vp[bh][s/32][d][s%32]
                    dst[bh16 + ((s >> 5) << 11) + d * 32 + (s & 31)] = (bf16_t)v;
                else          // qhp/khp[bh][d/32][s][d%32]
                    dst[bh16 + ((d >> 5) << 15) + s * 32 + (d & 31)] = (bf16_t)v;
            }
}

// ------------------------------------------------------------- output projection
__global__ __launch_bounds__(256, 3) void gemm_out(const bf16_t* __restrict__ A,
                                                   const bf16_t* __restrict__ BT,
                                                   float* __restrict__ out) {
    GEMM_BODY(A, BT)
#pragma unroll
    for (int i = 0; i < 4; ++i)
#pragma unroll
        for (int j = 0; j < 4; ++j)
#pragma unroll
            for (int r = 0; r < 4; ++r) {
                const int row = m_base + wm + i * 16 + lg * 4 + r;
                const int col = n_base + wn + j * 16 + lr;
                out[(size_t)row * 1024 + col] = acc[i][j][r];
            }
}

// --------------------------------------- fused scores+bias+softmax+attn-write+PV
// Round-6 structure (block = 16 q-rows, wave = 256 k-cols in registers) with
// 2-batch K and 2-batch V loads to cap peak live regs ~156, allowing
// __launch_bounds__(256,3) = 3 waves/SIMD (+50% latency hiding vs round 6).
__global__ __launch_bounds__(256, 3) void fused_attn(const bf16_t* __restrict__ qhp,
                                                     const bf16_t* __restrict__ khp,
                                                     const bf16_t* __restrict__ vp,
                                                     const float* __restrict__ bias,
                                                     float* __restrict__ attn,
                                                     bf16_t* __restrict__ ctxb) {
    __shared__ bf16_t plds[4][16][256];     // 32768 B: per-wave 16x256 P tile
    const int lane = threadIdx.x & 63;
    const int wave = threadIdx.x >> 6;
    const int lr = lane & 15, lg = lane >> 4;

    // decode: g&7 = xcd slot; per-xcd order: b fastest (shares bias tile), then qt
    const int g = blockIdx.x;
    const int j = g >> 3;
    const int h = (g & 7) + 8 * (j >> 8);
    const int qt = (j & 255) >> 2;
    const int b = j & 3;
    const int bh = b * 16 + h;
    const int m0 = qt * 16;

    // Q B-frag: lane holds Q[m0+lr][dk lg*8..+7] per half-plane
    const bf16_t* qbase = qhp + ((size_t)bh << 16);
    const bf16x8 aq0 = *reinterpret_cast<const bf16x8*>(qbase + (m0 + lr) * 32 + lg * 8);
    const bf16x8 aq1 = *reinterpret_cast<const bf16x8*>(qbase + 32768 + (m0 + lr) * 32 + lg * 8);

    const int c0 = wave * 256;              // this wave's k-col slice
    const bf16_t* kp0 = khp + ((size_t)bh << 16) + (size_t)(c0 + lr) * 32 + lg * 8;
    const float* brow = bias + ((size_t)h << 20) + (size_t)(m0 + lr) * 1024 + c0 + lg * 4;

    f32x4 acc[16];

    // ---- K batch 0: dk-half 0 for all 16 frags (16 x b128 in flight, 64 regs)
    {
        bf16x8 kf[16];
#pragma unroll
        for (int f = 0; f < 16; ++f)
            kf[f] = *reinterpret_cast<const bf16x8*>(kp0 + f * 512);
#pragma unroll
        for (int f = 0; f < 16; ++f) {
            const f32x4 z4 = {0.f, 0.f, 0.f, 0.f};
            acc[f] = MFMA16(kf[f], aq0, z4);
        }
    }
    // ---- K batch 1: dk-half 1
    {
        bf16x8 kf[16];
#pragma unroll
        for (int f = 0; f < 16; ++f)
            kf[f] = *reinterpret_cast<const bf16x8*>(kp0 + 32768 + f * 512);
#pragma unroll
        for (int f = 0; f < 16; ++f)
            acc[f] = MFMA16(kf[f], aq1, acc[f]);
    }
    // ---- bias (16 x f32x4, offsets immediate)
#pragma unroll
    for (int f = 0; f < 16; ++f) {
        f32x4 bv = *reinterpret_cast<const f32x4*>(brow + f * 16);
        acc[f] += bv;
    }

    float* smaxp = reinterpret_cast<float*>(&plds[0][0][0]);   // 64 f32 (aliased)
    float* ssump = smaxp + 64;                                 // 64 f32 (aliased)

    // ---- row max: in-lane over 64 values, shuffle xor16/32, LDS cross-wave
    f32x4 m4 = acc[0];
#pragma unroll
    for (int f = 1; f < 16; ++f) {
#pragma unroll
        for (int r = 0; r < 4; ++r) m4[r] = fmaxf(m4[r], acc[f][r]);
    }
    float mx = fmaxf(fmaxf(m4[0], m4[1]), fmaxf(m4[2], m4[3]));
    mx = fmaxf(mx, __shfl_xor(mx, 16));
    mx = fmaxf(mx, __shfl_xor(mx, 32));
    if (lane < 16) smaxp[wave * 16 + lr] = mx;
    __syncthreads();
    const float gm = fmaxf(fmaxf(smaxp[lr], smaxp[16 + lr]),
                           fmaxf(smaxp[32 + lr], smaxp[48 + lr]));

    // ---- exp once + row sum
    f32x4 s4 = {0.f, 0.f, 0.f, 0.f};
#pragma unroll
    for (int f = 0; f < 16; ++f) {
#pragma unroll
        for (int r = 0; r < 4; ++r) {
            const float e = __expf(acc[f][r] - gm);
            acc[f][r] = e;
            s4[r] += e;
        }
    }
    float sm = (s4[0] + s4[1]) + (s4[2] + s4[3]);
    sm += __shfl_xor(sm, 16);
    sm += __shfl_xor(sm, 32);
    if (lane < 16) ssump[wave * 16 + lr] = sm;
    __syncthreads();
    const float invl = 1.0f / (ssump[lr] + ssump[16 + lr] + ssump[32 + lr] + ssump[48 + lr]);
    __syncthreads();   // guard: smax/ssum alias the P region written below

    // ---- issue V batch 0 early (16 x b128; latency hides under attn stores)
    const bf16_t* vpb = vp + ((size_t)bh << 16) + (size_t)(wave * 8) * 2048 + lr * 32 + lg * 8;
    bf16x8 vf0[4][4];
#pragma unroll
    for (int ks = 0; ks < 4; ++ks)
#pragma unroll
        for (int f2 = 0; f2 < 4; ++f2)
            vf0[ks][f2] = *reinterpret_cast<const bf16x8*>(vpb + ks * 2048 + f2 * 512);

    // ---- write normalized attn (f32x4, offsets immediate) + pack P to LDS
    float* orow = attn + ((size_t)bh << 20) + (size_t)(m0 + lr) * 1024 + c0 + lg * 4;
    char* pw = reinterpret_cast<char*>(&plds[wave][0][0]);
    const int swz = (lr & 7) << 4;
#pragma unroll
    for (int f = 0; f < 16; ++f) {
        f32x4 v = acc[f];
#pragma unroll
        for (int r = 0; r < 4; ++r) v[r] *= invl;
        *reinterpret_cast<f32x4*>(orow + f * 16) = v;
        bf16x4 pb = { (bf16_t)v[0], (bf16_t)v[1], (bf16_t)v[2], (bf16_t)v[3] };
        *reinterpret_cast<bf16x4*>(pw + lr * 512 + ((f * 32 + lg * 8) ^ swz)) = pb;
    }
    // (no barrier: plds[wave] written and read only by this wave)

    // ---- PV half 0 (consume vf0) while issuing V batch 1
    f32x4 cacc[4];
#pragma unroll
    for (int f2 = 0; f2 < 4; ++f2) cacc[f2] = (f32x4){0.f, 0.f, 0.f, 0.f};

    bf16x8 vf1[4][4];
#pragma unroll
    for (int ks = 0; ks < 4; ++ks)
#pragma unroll
        for (int f2 = 0; f2 < 4; ++f2)
            vf1[ks][f2] = *reinterpret_cast<const bf16x8*>(vpb + (4 + ks) * 2048 + f2 * 512);

#pragma unroll
    for (int ks = 0; ks < 4; ++ks) {
        bf16x8 pa = *reinterpret_cast<const bf16x8*>(pw + lr * 512 + ((ks * 64 + lg * 16) ^ swz));
#pragma unroll
        for (int f2 = 0; f2 < 4; ++f2)
            cacc[f2] = MFMA16(pa, vf0[ks][f2], cacc[f2]);
    }
#pragma unroll
    for (int ks = 4; ks < 8; ++ks) {
        bf16x8 pa = *reinterpret_cast<const bf16x8*>(pw + lr * 512 + ((ks * 64 + lg * 16) ^ swz));
#pragma unroll
        for (int f2 = 0; f2 < 4; ++f2)
            cacc[f2] = MFMA16(pa, vf1[ks - 4][f2], cacc[f2]);
    }
    __syncthreads();   // all waves done with P tiles; re-alias as cred

    // ---- cross-wave ctx reduce via LDS (aliases plds)
    float* cred = reinterpret_cast<float*>(&plds[0][0][0]);    // [4][16][64] f32
#pragma unroll
    for (int f2 = 0; f2 < 4; ++f2)
#pragma unroll
        for (int r = 0; r < 4; ++r)
            cred[wave * 1024 + (lg * 4 + r) * 64 + f2 * 16 + lr] = cacc[f2][r];
    __syncthreads();
    const int row_l = wave * 4 + lg;
    const int dk0 = lr * 4;
    f32x4 s0 = *reinterpret_cast<const f32x4*>(&cred[0 * 1024 + row_l * 64 + dk0]);
    f32x4 s1 = *reinterpret_cast<const f32x4*>(&cred[1 * 1024 + row_l * 64 + dk0]);
    f32x4 s2 = *reinterpret_cast<const f32x4*>(&cred[2 * 1024 + row_l * 64 + dk0]);
    f32x4 s3 = *reinterpret_cast<const f32x4*>(&cred[3 * 1024 + row_l * 64 + dk0]);
    f32x4 st = (s0 + s1) + (s2 + s3);
    bf16x4 o4 = { (bf16_t)st[0], (bf16_t)st[1], (bf16_t)st[2], (bf16_t)st[3] };
    *reinterpret_cast<bf16x4*>(
        &ctxb[(size_t)(b * 1024 + m0 + row_l) * 1024 + h * 64 + dk0]) = o4;
}

// ---------------------------------------------------------------------- launcher
extern "C" void kernel_launch(void* const* d_in, const int* in_sizes, int n_in,
                              void* d_out, int out_size, void* d_ws, size_t ws_size,
                              hipStream_t stream) {
    const float* x    = (const float*)d_in[0];
    const float* bias = (const float*)d_in[1];
    const float* Wq   = (const float*)d_in[2];
    const float* Wk   = (const float*)d_in[3];
    const float* Wv   = (const float*)d_in[4];
    const float* Wo   = (const float*)d_in[5];
    float* out  = (float*)d_out;
    float* attn = out + (size_t)4 * 1024 * 1024;

    char* ws = (char*)d_ws;
    bf16_t* xb   = (bf16_t*)(ws);                      //  8 MB [4096,1024]
    bf16_t* wT   = (bf16_t*)(ws + ((size_t)8 << 20));  //  8 MB 4x [1024,1024] transposed
    bf16_t* qhp  = (bf16_t*)(ws + ((size_t)16 << 20)); //  8 MB Q/8 packed half-planes
    bf16_t* khp  = (bf16_t*)(ws + ((size_t)24 << 20)); //  8 MB K packed half-planes
    bf16_t* vp   = (bf16_t*)(ws + ((size_t)32 << 20)); //  8 MB V packed k-tiles
    bf16_t* ctxb = (bf16_t*)(ws + ((size_t)40 << 20)); //  8 MB ctx [B,S,D]
    bf16_t* woT = wT + ((size_t)3 << 20);

    cast_f32_bf16<<<dim3(4096), dim3(256), 0, stream>>>(x, xb, 1024 * 1024);
    transpose_cast_w<<<dim3(32, 32, 4), dim3(32, 32), 0, stream>>>(Wq, Wk, Wv, Wo, wT);

    gemm_qkv<<<dim3(32, 8, 3), dim3(256), 0, stream>>>(xb, wT, qhp, khp, vp);

    fused_attn<<<dim3(4096), dim3(256), 0, stream>>>(qhp, khp, vp, bias, attn, ctxb);

    gemm_out<<<dim3(32, 8), dim3(256), 0, stream>>>(ctxb, woT, out);
}

// Round 10
// 202.769 us; speedup vs baseline: 1.6996x; 1.0782x over previous
//
#include <hip/hip_runtime.h>
#include <hip/hip_bf16.h>

// MHA forward: B=4, S=1024, D=1024, H=16, DK=64
// outputs: out [4,1024,1024] f32, attn [4,16,1024,1024] f32 (concat in d_out)
//
// Packed operand layouts for the fused kernel (all bf16):
//   qhp/khp: [bh][half=dk/32][s][32]   -> frag loads 1KB contiguous
//   vp:      [bh][kb=s/32][dk][32]     -> PV frag loads 1KB contiguous

typedef __bf16 bf16_t;
typedef __bf16 bf16x4 __attribute__((ext_vector_type(4)));
typedef __bf16 bf16x8 __attribute__((ext_vector_type(8)));
typedef float f32x4 __attribute__((ext_vector_type(4)));

#define MFMA16(a, b, c) __builtin_amdgcn_mfma_f32_16x16x32_bf16(a, b, c, 0, 0, 0)

// ---------------------------------------------------------------- cast x -> bf16
__global__ __launch_bounds__(256) void cast_f32_bf16(const float* __restrict__ in,
                                                     bf16_t* __restrict__ out, int n4) {
    int i = blockIdx.x * blockDim.x + threadIdx.x;
    if (i >= n4) return;
    float4 v = reinterpret_cast<const float4*>(in)[i];
    bf16x4 o = { (bf16_t)v.x, (bf16_t)v.y, (bf16_t)v.z, (bf16_t)v.w };
    reinterpret_cast<bf16x4*>(out)[i] = o;
}

// ------------------------------------------- transpose + cast the 4 weight matrices
__global__ __launch_bounds__(1024) void transpose_cast_w(const float* __restrict__ w0,
                                                         const float* __restrict__ w1,
                                                         const float* __restrict__ w2,
                                                         const float* __restrict__ w3,
                                                         bf16_t* __restrict__ wt) {
    __shared__ float tile[32][33];
    const float* src = (blockIdx.z == 0) ? w0 : (blockIdx.z == 1) ? w1
                     : (blockIdx.z == 2) ? w2 : w3;
    bf16_t* dst = wt + (size_t)blockIdx.z * 1024 * 1024;
    int r0 = blockIdx.y * 32, c0 = blockIdx.x * 32;
    tile[threadIdx.y][threadIdx.x] = src[(size_t)(r0 + threadIdx.y) * 1024 + c0 + threadIdx.x];
    __syncthreads();
    dst[(size_t)(c0 + threadIdx.y) * 1024 + r0 + threadIdx.x] = (bf16_t)tile[threadIdx.x][threadIdx.y];
}

// ------------------------------------------------------- GEMM core (128x128 tile)
// block = 256 threads = 4 waves (2x2), each wave 64x64 output (4x4 frags)
#define GEMM_BODY(A, BT)                                                                 \
    __shared__ bf16_t As[128 * 32];                                                      \
    __shared__ bf16_t Bs[128 * 32];                                                      \
    const int tid = threadIdx.x;                                                         \
    const int lane = tid & 63, wave = tid >> 6;                                          \
    const int lr = lane & 15, lg = lane >> 4;                                            \
    const int m_base = blockIdx.x * 128, n_base = blockIdx.y * 128;                      \
    const int wm = (wave >> 1) * 64, wn = (wave & 1) * 64;                               \
    const int srow = tid >> 1;                                                           \
    const int sl0 = (tid & 1) * 2;                                                       \
    const int sl1 = sl0 + 1;                                                             \
    const int off0 = srow * 32 + ((sl0 ^ ((srow >> 1) & 3)) * 8);                        \
    const int off1 = srow * 32 + ((sl1 ^ ((srow >> 1) & 3)) * 8);                        \
    const bf16_t* aptr = (A) + (size_t)(m_base + srow) * 1024 + sl0 * 8;                 \
    const bf16_t* bptr = (BT) + (size_t)(n_base + srow) * 1024 + sl0 * 8;                \
    bf16x8 ra0 = *reinterpret_cast<const bf16x8*>(aptr);                                 \
    bf16x8 ra1 = *reinterpret_cast<const bf16x8*>(aptr + 8);                             \
    bf16x8 rb0 = *reinterpret_cast<const bf16x8*>(bptr);                                 \
    bf16x8 rb1 = *reinterpret_cast<const bf16x8*>(bptr + 8);                             \
    f32x4 acc[4][4] = {};                                                                \
    for (int kb = 32; kb <= 1024; kb += 32) {                                            \
        __syncthreads();                                                                 \
        *reinterpret_cast<bf16x8*>(&As[off0]) = ra0;                                     \
        *reinterpret_cast<bf16x8*>(&As[off1]) = ra1;                                     \
        *reinterpret_cast<bf16x8*>(&Bs[off0]) = rb0;                                     \
        *reinterpret_cast<bf16x8*>(&Bs[off1]) = rb1;                                     \
        if (kb < 1024) {                                                                 \
            ra0 = *reinterpret_cast<const bf16x8*>(aptr + kb);                           \
            ra1 = *reinterpret_cast<const bf16x8*>(aptr + kb + 8);                       \
            rb0 = *reinterpret_cast<const bf16x8*>(bptr + kb);                           \
            rb1 = *reinterpret_cast<const bf16x8*>(bptr + kb + 8);                       \
        }                                                                                \
        __syncthreads();                                                                 \
        bf16x8 af[4], bfr[4];                                                            \
        _Pragma("unroll") for (int i = 0; i < 4; ++i) {                                  \
            const int row = wm + i * 16 + lr;                                            \
            af[i] = *reinterpret_cast<const bf16x8*>(                                    \
                &As[row * 32 + ((lg ^ ((row >> 1) & 3)) * 8)]);                          \
        }                                                                                \
        _Pragma("unroll") for (int j = 0; j < 4; ++j) {                                  \
            const int row = wn + j * 16 + lr;                                            \
            bfr[j] = *reinterpret_cast<const bf16x8*>(                                   \
                &Bs[row * 32 + ((lg ^ ((row >> 1) & 3)) * 8)]);                          \
        }                                                                                \
        _Pragma("unroll") for (int i = 0; i < 4; ++i)                                    \
            _Pragma("unroll") for (int j = 0; j < 4; ++j)                                \
                acc[i][j] = MFMA16(af[i], bfr[j], acc[i][j]);                            \
    }

// ---------------------------------------------------- QKV projections, one launch
// blockIdx.z: 0 = Q -> qhp (x0.125), 1 = K -> khp, 2 = V -> vp
__global__ __launch_bounds__(256, 3) void gemm_qkv(const bf16_t* __restrict__ A,
                                                   const bf16_t* __restrict__ wT,
                                                   bf16_t* __restrict__ qhp,
                                                   bf16_t* __restrict__ khp,
                                                   bf16_t* __restrict__ vp) {
    const int z = blockIdx.z;
    const bf16_t* BT = wT + ((size_t)z << 20);
    GEMM_BODY(A, BT)
    bf16_t* dst = (z == 0) ? qhp : (z == 1) ? khp : vp;
    const float scale = (z == 0) ? 0.125f : 1.0f;
#pragma unroll
    for (int i = 0; i < 4; ++i)
#pragma unroll
        for (int j = 0; j < 4; ++j)
#pragma unroll
            for (int r = 0; r < 4; ++r) {
                const int row = m_base + wm + i * 16 + lg * 4 + r;
                const int col = n_base + wn + j * 16 + lr;
                const float v = acc[i][j][r] * scale;
                const int b = row >> 10, s = row & 1023;
                const int h = col >> 6, d = col & 63;
                const size_t bh16 = (size_t)(b * 16 + h) << 16;
                if (z == 2)   // vp[bh][s/32][d][s%32]
                    dst[bh16 + ((s >> 5) << 11) + d * 32 + (s & 31)] = (bf16_t)v;
                else          // qhp/khp[bh][d/32][s][d%32]
                    dst[bh16 + ((d >> 5) << 15) + s * 32 + (d & 31)] = (bf16_t)v;
            }
}

// ------------------------------------------------------------- output projection
__global__ __launch_bounds__(256, 3) void gemm_out(const bf16_t* __restrict__ A,
                                                   const bf16_t* __restrict__ BT,
                                                   float* __restrict__ out) {
    GEMM_BODY(A, BT)
#pragma unroll
    for (int i = 0; i < 4; ++i)
#pragma unroll
        for (int j = 0; j < 4; ++j)
#pragma unroll
            for (int r = 0; r < 4; ++r) {
                const int row = m_base + wm + i * 16 + lg * 4 + r;
                const int col = n_base + wn + j * 16 + lr;
                out[(size_t)row * 1024 + col] = acc[i][j][r];
            }
}

// --------------------------------------- fused scores+bias+softmax+attn-write+PV
// SEGMENT-COALESCED (fixed): bias reads and attn writes go through a per-wave
// 16KB LDS f32 tile so every global access is ONE contiguous 1KB segment per
// instruction. Swizzle discipline (rule #21): global address carries the lane
// permutation co = 4*(lane^(i&7)); LDS address is LINEAR (i*1024 + lane*16).
// That stores content(C) at position C ^ ((row&7)<<4), matching the
// frag-order accesses' ^((lr&7)<<4). P for PV is read back from the same
// tile (f32 -> bf16 cvt in-register); cred reduce reuses the tile region.
__global__ __launch_bounds__(256, 2) void fused_attn(const bf16_t* __restrict__ qhp,
                                                     const bf16_t* __restrict__ khp,
                                                     const bf16_t* __restrict__ vp,
                                                     const float* __restrict__ bias,
                                                     float* __restrict__ attn,
                                                     bf16_t* __restrict__ ctxb) {
    __shared__ float ftile[4][16][256];     // 65536 B: per-wave 16x256 f32 tile
    __shared__ float smaxp[64];
    __shared__ float ssump[64];
    const int lane = threadIdx.x & 63;
    const int wave = threadIdx.x >> 6;
    const int lr = lane & 15, lg = lane >> 4;

    // decode: g&7 = xcd slot; per-xcd order: b fastest (shares bias tile), then qt
    const int g = blockIdx.x;
    const int j = g >> 3;
    const int h = (g & 7) + 8 * (j >> 8);
    const int qt = (j & 255) >> 2;
    const int b = j & 3;
    const int bh = b * 16 + h;
    const int m0 = qt * 16;

    // Q B-frag: lane holds Q[m0+lr][dk lg*8..+7] per half-plane
    const bf16_t* qbase = qhp + ((size_t)bh << 16);
    const bf16x8 aq0 = *reinterpret_cast<const bf16x8*>(qbase + (m0 + lr) * 32 + lg * 8);
    const bf16x8 aq1 = *reinterpret_cast<const bf16x8*>(qbase + 32768 + (m0 + lr) * 32 + lg * 8);

    const int c0 = wave * 256;              // this wave's k-col slice
    const bf16_t* kp0 = khp + ((size_t)bh << 16) + (size_t)(c0 + lr) * 32 + lg * 8;

    char* tw = reinterpret_cast<char*>(&ftile[wave][0][0]);
    const int myswz = (lr & 7) << 4;        // byte XOR for frag-order row access

    // ---- phase 0a: issue K batch 0 (16 x b128, 1KB contiguous each)
    bf16x8 kfA[16];
#pragma unroll
    for (int f = 0; f < 16; ++f)
        kfA[f] = *reinterpret_cast<const bf16x8*>(kp0 + f * 512);

    // ---- phase 0b: bias rows -> LDS tile. Global col permuted, LDS dest LINEAR
    //      => tile holds content(C) at byte position C ^ ((row&7)<<4).
    {
        const float* bbase = bias + ((size_t)h << 20) + (size_t)m0 * 1024 + c0;
#pragma unroll
        for (int i = 0; i < 16; ++i) {
            const int co = (lane * 4) ^ ((i & 7) * 4);   // permuted global f32 col
            f32x4 bv = *reinterpret_cast<const f32x4*>(bbase + (size_t)i * 1024 + co);
            *reinterpret_cast<f32x4*>(tw + i * 1024 + lane * 16) = bv;
        }
    }

    // ---- phase 0c: acc init = bias fragments (frag-order swizzled LDS read)
    f32x4 acc[16];
#pragma unroll
    for (int f = 0; f < 16; ++f)
        acc[f] = *reinterpret_cast<const f32x4*>(tw + lr * 1024 + ((f * 64 + lg * 16) ^ myswz));

    // ---- phase 1: QK^T (swapped) accumulating onto bias
#pragma unroll
    for (int f = 0; f < 16; ++f)
        acc[f] = MFMA16(kfA[f], aq0, acc[f]);
    {
        bf16x8 kfB[16];
#pragma unroll
        for (int f = 0; f < 16; ++f)
            kfB[f] = *reinterpret_cast<const bf16x8*>(kp0 + 32768 + f * 512);
#pragma unroll
        for (int f = 0; f < 16; ++f)
            acc[f] = MFMA16(kfB[f], aq1, acc[f]);
    }

    // ---- row max: in-lane over 64 values, shuffle xor16/32, LDS cross-wave
    f32x4 m4 = acc[0];
#pragma unroll
    for (int f = 1; f < 16; ++f) {
#pragma unroll
        for (int r = 0; r < 4; ++r) m4[r] = fmaxf(m4[r], acc[f][r]);
    }
    float mx = fmaxf(fmaxf(m4[0], m4[1]), fmaxf(m4[2], m4[3]));
    mx = fmaxf(mx, __shfl_xor(mx, 16));
    mx = fmaxf(mx, __shfl_xor(mx, 32));
    if (lane < 16) smaxp[wave * 16 + lr] = mx;
    __syncthreads();
    const float gm = fmaxf(fmaxf(smaxp[lr], smaxp[16 + lr]),
                           fmaxf(smaxp[32 + lr], smaxp[48 + lr]));

    // ---- exp once + row sum
    f32x4 s4 = {0.f, 0.f, 0.f, 0.f};
#pragma unroll
    for (int f = 0; f < 16; ++f) {
#pragma unroll
        for (int r = 0; r < 4; ++r) {
            const float e = __expf(acc[f][r] - gm);
            acc[f][r] = e;
            s4[r] += e;
        }
    }
    float sm = (s4[0] + s4[1]) + (s4[2] + s4[3]);
    sm += __shfl_xor(sm, 16);
    sm += __shfl_xor(sm, 32);
    if (lane < 16) ssump[wave * 16 + lr] = sm;
    __syncthreads();
    const float invl = 1.0f / (ssump[lr] + ssump[16 + lr] + ssump[32 + lr] + ssump[48 + lr]);

    // ---- issue V batch 0 early (latency hides under the store phase)
    const bf16_t* vpb = vp + ((size_t)bh << 16) + (size_t)(wave * 8) * 2048 + lr * 32 + lg * 8;
    bf16x8 vf0[4][4];
#pragma unroll
    for (int ks = 0; ks < 4; ++ks)
#pragma unroll
        for (int f2 = 0; f2 < 4; ++f2)
            vf0[ks][f2] = *reinterpret_cast<const bf16x8*>(vpb + ks * 2048 + f2 * 512);

    // ---- normalize -> frag-order swizzled LDS write (P tile, f32)
#pragma unroll
    for (int f = 0; f < 16; ++f) {
        f32x4 v = acc[f];
#pragma unroll
        for (int r = 0; r < 4; ++r) v[r] *= invl;
        *reinterpret_cast<f32x4*>(tw + lr * 1024 + ((f * 64 + lg * 16) ^ myswz)) = v;
    }

    // ---- attn stores: LINEAR LDS read + permuted-col global store (1KB contig)
    {
        float* obase = attn + ((size_t)bh << 20) + (size_t)m0 * 1024 + c0;
#pragma unroll
        for (int i = 0; i < 16; ++i) {
            const int co = (lane * 4) ^ ((i & 7) * 4);
            f32x4 v = *reinterpret_cast<const f32x4*>(tw + i * 1024 + lane * 16);
            *reinterpret_cast<f32x4*>(obase + (size_t)i * 1024 + co) = v;
        }
    }

    // ---- PV: A = P from f32 tile (cvt to bf16), B = V reg batches
    f32x4 cacc[4];
#pragma unroll
    for (int f2 = 0; f2 < 4; ++f2) cacc[f2] = (f32x4){0.f, 0.f, 0.f, 0.f};

    bf16x8 vf1[4][4];
#pragma unroll
    for (int ks = 0; ks < 4; ++ks)
#pragma unroll
        for (int f2 = 0; f2 < 4; ++f2)
            vf1[ks][f2] = *reinterpret_cast<const bf16x8*>(vpb + (4 + ks) * 2048 + f2 * 512);

#pragma unroll
    for (int ks = 0; ks < 8; ++ks) {
        f32x4 p0 = *reinterpret_cast<const f32x4*>(
            tw + lr * 1024 + ((ks * 128 + lg * 32) ^ myswz));
        f32x4 p1 = *reinterpret_cast<const f32x4*>(
            tw + lr * 1024 + ((ks * 128 + lg * 32 + 16) ^ myswz));
        bf16x8 pa = { (bf16_t)p0[0], (bf16_t)p0[1], (bf16_t)p0[2], (bf16_t)p0[3],
                      (bf16_t)p1[0], (bf16_t)p1[1], (bf16_t)p1[2], (bf16_t)p1[3] };
#pragma unroll
        for (int f2 = 0; f2 < 4; ++f2)
            cacc[f2] = MFMA16(pa, (ks < 4) ? vf0[ks & 3][f2] : vf1[ks & 3][f2], cacc[f2]);
    }

    // ---- cross-wave ctx reduce (reuse own tile region; barrier-protected)
    float* credw = &ftile[wave][0][0];      // 1024 f32 = [16 rows][64 dk]
#pragma unroll
    for (int f2 = 0; f2 < 4; ++f2)
#pragma unroll
        for (int r = 0; r < 4; ++r)
            credw[(lg * 4 + r) * 64 + f2 * 16 + lr] = cacc[f2][r];
    __syncthreads();
    const int row_l = wave * 4 + lg;
    const int dk0 = lr * 4;
    f32x4 s0 = *reinterpret_cast<const f32x4*>(&ftile[0][0][0] + row_l * 64 + dk0);
    f32x4 s1 = *reinterpret_cast<const f32x4*>(&ftile[1][0][0] + row_l * 64 + dk0);
    f32x4 s2 = *reinterpret_cast<const f32x4*>(&ftile[2][0][0] + row_l * 64 + dk0);
    f32x4 s3 = *reinterpret_cast<const f32x4*>(&ftile[3][0][0] + row_l * 64 + dk0);
    f32x4 st = (s0 + s1) + (s2 + s3);
    bf16x4 o4 = { (bf16_t)st[0], (bf16_t)st[1], (bf16_t)st[2], (bf16_t)st[3] };
    *reinterpret_cast<bf16x4*>(
        &ctxb[(size_t)(b * 1024 + m0 + row_l) * 1024 + h * 64 + dk0]) = o4;
}

// ---------------------------------------------------------------------- launcher
extern "C" void kernel_launch(void* const* d_in, const int* in_sizes, int n_in,
                              void* d_out, int out_size, void* d_ws, size_t ws_size,
                              hipStream_t stream) {
    const float* x    = (const float*)d_in[0];
    const float* bias = (const float*)d_in[1];
    const float* Wq   = (const float*)d_in[2];
    const float* Wk   = (const float*)d_in[3];
    const float* Wv   = (const float*)d_in[4];
    const float* Wo   = (const float*)d_in[5];
    float* out  = (float*)d_out;
    float* attn = out + (size_t)4 * 1024 * 1024;

    char* ws = (char*)d_ws;
    bf16_t* xb   = (bf16_t*)(ws);                      //  8 MB [4096,1024]
    bf16_t* wT   = (bf16_t*)(ws + ((size_t)8 << 20));  //  8 MB 4x [1024,1024] transposed
    bf16_t* qhp  = (bf16_t*)(ws + ((size_t)16 << 20)); //  8 MB Q/8 packed half-planes
    bf16_t* khp  = (bf16_t*)(ws + ((size_t)24 << 20)); //  8 MB K packed half-planes
    bf16_t* vp   = (bf16_t*)(ws + ((size_t)32 << 20)); //  8 MB V packed k-tiles
    bf16_t* ctxb = (bf16_t*)(ws + ((size_t)40 << 20)); //  8 MB ctx [B,S,D]
    bf16_t* woT = wT + ((size_t)3 << 20);

    cast_f32_bf16<<<dim3(4096), dim3(256), 0, stream>>>(x, xb, 1024 * 1024);
    transpose_cast_w<<<dim3(32, 32, 4), dim3(32, 32), 0, stream>>>(Wq, Wk, Wv, Wo, wT);

    gemm_qkv<<<dim3(32, 8, 3), dim3(256), 0, stream>>>(xb, wT, qhp, khp, vp);

    fused_attn<<<dim3(4096), dim3(256), 0, stream>>>(qhp, khp, vp, bias, attn, ctxb);

    gemm_out<<<dim3(32, 8), dim3(256), 0, stream>>>(ctxb, woT, out);
}

// Round 11
// 180.788 us; speedup vs baseline: 1.9062x; 1.1216x over previous
//
#include <hip/hip_runtime.h>
#include <hip/hip_bf16.h>

// MHA forward: B=4, S=1024, D=1024, H=16, DK=64
// outputs: out [4,1024,1024] f32, attn [4,16,1024,1024] f32 (concat in d_out)
//
// Packed operand layouts for the fused kernel (all bf16):
//   qhp/khp: [bh][half=dk/32][s][32]   -> frag loads 1KB contiguous
//   vp:      [bh][kb=s/32][dk][32]     -> PV frag loads 1KB contiguous

typedef __bf16 bf16_t;
typedef __bf16 bf16x4 __attribute__((ext_vector_type(4)));
typedef __bf16 bf16x8 __attribute__((ext_vector_type(8)));
typedef float f32x4 __attribute__((ext_vector_type(4)));

#define MFMA16(a, b, c) __builtin_amdgcn_mfma_f32_16x16x32_bf16(a, b, c, 0, 0, 0)

// ---------------------------------------------------------------- cast x -> bf16
__global__ __launch_bounds__(256) void cast_f32_bf16(const float* __restrict__ in,
                                                     bf16_t* __restrict__ out, int n4) {
    int i = blockIdx.x * blockDim.x + threadIdx.x;
    if (i >= n4) return;
    float4 v = reinterpret_cast<const float4*>(in)[i];
    bf16x4 o = { (bf16_t)v.x, (bf16_t)v.y, (bf16_t)v.z, (bf16_t)v.w };
    reinterpret_cast<bf16x4*>(out)[i] = o;
}

// ------------------------------------------- transpose + cast the 4 weight matrices
__global__ __launch_bounds__(1024) void transpose_cast_w(const float* __restrict__ w0,
                                                         const float* __restrict__ w1,
                                                         const float* __restrict__ w2,
                                                         const float* __restrict__ w3,
                                                         bf16_t* __restrict__ wt) {
    __shared__ float tile[32][33];
    const float* src = (blockIdx.z == 0) ? w0 : (blockIdx.z == 1) ? w1
                     : (blockIdx.z == 2) ? w2 : w3;
    bf16_t* dst = wt + (size_t)blockIdx.z * 1024 * 1024;
    int r0 = blockIdx.y * 32, c0 = blockIdx.x * 32;
    tile[threadIdx.y][threadIdx.x] = src[(size_t)(r0 + threadIdx.y) * 1024 + c0 + threadIdx.x];
    __syncthreads();
    dst[(size_t)(c0 + threadIdx.y) * 1024 + r0 + threadIdx.x] = (bf16_t)tile[threadIdx.x][threadIdx.y];
}

// ------------------------------------------------------- GEMM core (128x128 tile)
// block = 256 threads = 4 waves (2x2), each wave 64x64 output (4x4 frags)
#define GEMM_BODY(A, BT)                                                                 \
    __shared__ bf16_t As[128 * 32];                                                      \
    __shared__ bf16_t Bs[128 * 32];                                                      \
    const int tid = threadIdx.x;                                                         \
    const int lane = tid & 63, wave = tid >> 6;                                          \
    const int lr = lane & 15, lg = lane >> 4;                                            \
    const int m_base = blockIdx.x * 128, n_base = blockIdx.y * 128;                      \
    const int wm = (wave >> 1) * 64, wn = (wave & 1) * 64;                               \
    const int srow = tid >> 1;                                                           \
    const int sl0 = (tid & 1) * 2;                                                       \
    const int sl1 = sl0 + 1;                                                             \
    const int off0 = srow * 32 + ((sl0 ^ ((srow >> 1) & 3)) * 8);                        \
    const int off1 = srow * 32 + ((sl1 ^ ((srow >> 1) & 3)) * 8);                        \
    const bf16_t* aptr = (A) + (size_t)(m_base + srow) * 1024 + sl0 * 8;                 \
    const bf16_t* bptr = (BT) + (size_t)(n_base + srow) * 1024 + sl0 * 8;                \
    bf16x8 ra0 = *reinterpret_cast<const bf16x8*>(aptr);                                 \
    bf16x8 ra1 = *reinterpret_cast<const bf16x8*>(aptr + 8);                             \
    bf16x8 rb0 = *reinterpret_cast<const bf16x8*>(bptr);                                 \
    bf16x8 rb1 = *reinterpret_cast<const bf16x8*>(bptr + 8);                             \
    f32x4 acc[4][4] = {};                                                                \
    for (int kb = 32; kb <= 1024; kb += 32) {                                            \
        __syncthreads();                                                                 \
        *reinterpret_cast<bf16x8*>(&As[off0]) = ra0;                                     \
        *reinterpret_cast<bf16x8*>(&As[off1]) = ra1;                                     \
        *reinterpret_cast<bf16x8*>(&Bs[off0]) = rb0;                                     \
        *reinterpret_cast<bf16x8*>(&Bs[off1]) = rb1;                                     \
        if (kb < 1024) {                                                                 \
            ra0 = *reinterpret_cast<const bf16x8*>(aptr + kb);                           \
            ra1 = *reinterpret_cast<const bf16x8*>(aptr + kb + 8);                       \
            rb0 = *reinterpret_cast<const bf16x8*>(bptr + kb);                           \
            rb1 = *reinterpret_cast<const bf16x8*>(bptr + kb + 8);                       \
        }                                                                                \
        __syncthreads();                                                                 \
        bf16x8 af[4], bfr[4];                                                            \
        _Pragma("unroll") for (int i = 0; i < 4; ++i) {                                  \
            const int row = wm + i * 16 + lr;                                            \
            af[i] = *reinterpret_cast<const bf16x8*>(                                    \
                &As[row * 32 + ((lg ^ ((row >> 1) & 3)) * 8)]);                          \
        }                                                                                \
        _Pragma("unroll") for (int j = 0; j < 4; ++j) {                                  \
            const int row = wn + j * 16 + lr;                                            \
            bfr[j] = *reinterpret_cast<const bf16x8*>(                                   \
                &Bs[row * 32 + ((lg ^ ((row >> 1) & 3)) * 8)]);                          \
        }                                                                                \
        _Pragma("unroll") for (int i = 0; i < 4; ++i)                                    \
            _Pragma("unroll") for (int j = 0; j < 4; ++j)                                \
                acc[i][j] = MFMA16(af[i], bfr[j], acc[i][j]);                            \
    }

// ---------------------------------------------------- QKV projections, one launch
// blockIdx.z: 0 = Q -> qhp (x0.125), 1 = K -> khp, 2 = V -> vp
__global__ __launch_bounds__(256, 3) void gemm_qkv(const bf16_t* __restrict__ A,
                                                   const bf16_t* __restrict__ wT,
                                                   bf16_t* __restrict__ qhp,
                                                   bf16_t* __restrict__ khp,
                                                   bf16_t* __restrict__ vp) {
    const int z = blockIdx.z;
    const bf16_t* BT = wT + ((size_t)z << 20);
    GEMM_BODY(A, BT)
    bf16_t* dst = (z == 0) ? qhp : (z == 1) ? khp : vp;
    const float scale = (z == 0) ? 0.125f : 1.0f;
#pragma unroll
    for (int i = 0; i < 4; ++i)
#pragma unroll
        for (int j = 0; j < 4; ++j)
#pragma unroll
            for (int r = 0; r < 4; ++r) {
                const int row = m_base + wm + i * 16 + lg * 4 + r;
                const int col = n_base + wn + j * 16 + lr;
                const float v = acc[i][j][r] * scale;
                const int b = row >> 10, s = row & 1023;
                const int h = col >> 6, d = col & 63;
                const size_t bh16 = (size_t)(b * 16 + h) << 16;
                if (z == 2)   // vp[bh][s/32][d][s%32]
                    dst[bh16 + ((s >> 5) << 11) + d * 32 + (s & 31)] = (bf16_t)v;
                else          // qhp/khp[bh][d/32][s][d%32]
                    dst[bh16 + ((d >> 5) << 15) + s * 32 + (d & 31)] = (bf16_t)v;
            }
}

// ------------------------------------------------------------- output projection
__global__ __launch_bounds__(256, 3) void gemm_out(const bf16_t* __restrict__ A,
                                                   const bf16_t* __restrict__ BT,
                                                   float* __restrict__ out) {
    GEMM_BODY(A, BT)
#pragma unroll
    for (int i = 0; i < 4; ++i)
#pragma unroll
        for (int j = 0; j < 4; ++j)
#pragma unroll
            for (int r = 0; r < 4; ++r) {
                const int row = m_base + wm + i * 16 + lg * 4 + r;
                const int col = n_base + wn + j * 16 + lr;
                out[(size_t)row * 1024 + col] = acc[i][j][r];
            }
}

// --------------------------------------- fused scores+bias+softmax+attn-write+PV
// 2-Q-TILE version: block = 32 q-rows (2 tiles of 16) of one (b,h); wave owns a
// 256-col slice for BOTH tiles. K loaded once (4 transient batches of 8 frags,
// straight-line code -> no cross-loop register residency), V loaded once and
// shared by both PV phases. Per-wave 16KB LDS region time-shared:
//   bias0(f32) -> acc0 init; bias1(f32) -> acc1 init; P0(bf16)@0 + P1(bf16)@8K;
//   cred f32 [2][16][64] @0 (after PV). attn stores read the bf16 P tiles
//   (attn values <= ~0.05 -> bf16 rounding error <= ~2e-4, within threshold).
__global__ __launch_bounds__(256, 2) void fused_attn(const bf16_t* __restrict__ qhp,
                                                     const bf16_t* __restrict__ khp,
                                                     const bf16_t* __restrict__ vp,
                                                     const float* __restrict__ bias,
                                                     float* __restrict__ attn,
                                                     bf16_t* __restrict__ ctxb) {
    __shared__ f32x4 wlds4[4][1024];        // 65536 B: per-wave 16KB region
    __shared__ float smaxp[128];            // [tile][wave*16+q]
    __shared__ float ssump[128];
    const int lane = threadIdx.x & 63;
    const int wave = threadIdx.x >> 6;
    const int lr = lane & 15, lg = lane >> 4;

    // decode 2048 blocks: g&7 = xcd slot; per-xcd: b fastest, qt, then h-ext
    const int g = blockIdx.x;
    const int j = g >> 3;                   // 0..255
    const int h = (g & 7) + 8 * (j >> 7);   // 0..15
    const int qt = (j >> 2) & 31;           // 32-row q-tile
    const int b = j & 3;
    const int bh = b * 16 + h;
    const int m0 = qt * 32;                 // tile0: m0..+15, tile1: m0+16..+31

    // Q B-frags for both tiles
    const bf16_t* qbase = qhp + ((size_t)bh << 16);
    const bf16x8 aqA0 = *reinterpret_cast<const bf16x8*>(qbase + (m0 + lr) * 32 + lg * 8);
    const bf16x8 aqA1 = *reinterpret_cast<const bf16x8*>(qbase + 32768 + (m0 + lr) * 32 + lg * 8);
    const bf16x8 aqB0 = *reinterpret_cast<const bf16x8*>(qbase + (m0 + 16 + lr) * 32 + lg * 8);
    const bf16x8 aqB1 = *reinterpret_cast<const bf16x8*>(qbase + 32768 + (m0 + 16 + lr) * 32 + lg * 8);

    const int c0 = wave * 256;              // this wave's k-col slice
    const bf16_t* kp0 = khp + ((size_t)bh << 16) + (size_t)(c0 + lr) * 32 + lg * 8;

    char* tw = reinterpret_cast<char*>(&wlds4[wave][0]);
    const int myswz = (lr & 7) << 4;

    // ---- bias tile0 -> LDS (permuted global col, linear LDS dest = swizzled tile)
    const float* bb0 = bias + ((size_t)h << 20) + (size_t)m0 * 1024 + c0;
#pragma unroll
    for (int i = 0; i < 16; ++i) {
        const int co = (lane * 4) ^ ((i & 7) * 4);
        f32x4 bv = *reinterpret_cast<const f32x4*>(bb0 + (size_t)i * 1024 + co);
        *reinterpret_cast<f32x4*>(tw + i * 1024 + lane * 16) = bv;
    }
    f32x4 acc0[16];
#pragma unroll
    for (int f = 0; f < 16; ++f)
        acc0[f] = *reinterpret_cast<const f32x4*>(tw + lr * 1024 + ((f * 64 + lg * 16) ^ myswz));

    // ---- bias tile1 -> LDS (reuse region), init acc1
    const float* bb1 = bb0 + 16 * 1024;
#pragma unroll
    for (int i = 0; i < 16; ++i) {
        const int co = (lane * 4) ^ ((i & 7) * 4);
        f32x4 bv = *reinterpret_cast<const f32x4*>(bb1 + (size_t)i * 1024 + co);
        *reinterpret_cast<f32x4*>(tw + i * 1024 + lane * 16) = bv;
    }
    f32x4 acc1[16];
#pragma unroll
    for (int f = 0; f < 16; ++f)
        acc1[f] = *reinterpret_cast<const f32x4*>(tw + lr * 1024 + ((f * 64 + lg * 16) ^ myswz));

    // ---- QK^T (swapped) for both tiles; K in 4 transient batches of 8 frags
#pragma unroll
    for (int half = 0; half < 2; ++half) {
        const bf16x8 aqA = half ? aqA1 : aqA0;
        const bf16x8 aqB = half ? aqB1 : aqB0;
#pragma unroll
        for (int bt = 0; bt < 2; ++bt) {
            bf16x8 kf[8];
#pragma unroll
            for (int u = 0; u < 8; ++u)
                kf[u] = *reinterpret_cast<const bf16x8*>(
                    kp0 + half * 32768 + (bt * 8 + u) * 512);
#pragma unroll
            for (int u = 0; u < 8; ++u) {
                acc0[bt * 8 + u] = MFMA16(kf[u], aqA, acc0[bt * 8 + u]);
                acc1[bt * 8 + u] = MFMA16(kf[u], aqB, acc1[bt * 8 + u]);
            }
        }
    }

    // ---- row max (both tiles): in-lane over 64 + shuffle xor16/32 + LDS
    f32x4 m40 = acc0[0], m41 = acc1[0];
#pragma unroll
    for (int f = 1; f < 16; ++f) {
#pragma unroll
        for (int r = 0; r < 4; ++r) {
            m40[r] = fmaxf(m40[r], acc0[f][r]);
            m41[r] = fmaxf(m41[r], acc1[f][r]);
        }
    }
    float mx0 = fmaxf(fmaxf(m40[0], m40[1]), fmaxf(m40[2], m40[3]));
    float mx1 = fmaxf(fmaxf(m41[0], m41[1]), fmaxf(m41[2], m41[3]));
    mx0 = fmaxf(mx0, __shfl_xor(mx0, 16));
    mx0 = fmaxf(mx0, __shfl_xor(mx0, 32));
    mx1 = fmaxf(mx1, __shfl_xor(mx1, 16));
    mx1 = fmaxf(mx1, __shfl_xor(mx1, 32));
    if (lane < 16) {
        smaxp[wave * 16 + lr] = mx0;
        smaxp[64 + wave * 16 + lr] = mx1;
    }
    __syncthreads();
    const float gm0 = fmaxf(fmaxf(smaxp[lr], smaxp[16 + lr]),
                            fmaxf(smaxp[32 + lr], smaxp[48 + lr]));
    const float gm1 = fmaxf(fmaxf(smaxp[64 + lr], smaxp[80 + lr]),
                            fmaxf(smaxp[96 + lr], smaxp[112 + lr]));

    // ---- exp once + row sums (both tiles)
    f32x4 s40 = {0.f, 0.f, 0.f, 0.f}, s41 = {0.f, 0.f, 0.f, 0.f};
#pragma unroll
    for (int f = 0; f < 16; ++f) {
#pragma unroll
        for (int r = 0; r < 4; ++r) {
            const float e0 = __expf(acc0[f][r] - gm0);
            const float e1 = __expf(acc1[f][r] - gm1);
            acc0[f][r] = e0;
            acc1[f][r] = e1;
            s40[r] += e0;
            s41[r] += e1;
        }
    }
    float sm0 = (s40[0] + s40[1]) + (s40[2] + s40[3]);
    float sm1 = (s41[0] + s41[1]) + (s41[2] + s41[3]);
    sm0 += __shfl_xor(sm0, 16);
    sm0 += __shfl_xor(sm0, 32);
    sm1 += __shfl_xor(sm1, 16);
    sm1 += __shfl_xor(sm1, 32);
    if (lane < 16) {
        ssump[wave * 16 + lr] = sm0;
        ssump[64 + wave * 16 + lr] = sm1;
    }
    __syncthreads();
    const float invl0 = 1.0f / (ssump[lr] + ssump[16 + lr] + ssump[32 + lr] + ssump[48 + lr]);
    const float invl1 = 1.0f / (ssump[64 + lr] + ssump[80 + lr] + ssump[96 + lr] + ssump[112 + lr]);

    // ---- issue V batch 0 early (shared by both tiles' PV)
    const bf16_t* vpb = vp + ((size_t)bh << 16) + (size_t)(wave * 8) * 2048 + lr * 32 + lg * 8;
    bf16x8 vf0[4][4];
#pragma unroll
    for (int ks = 0; ks < 4; ++ks)
#pragma unroll
        for (int f2 = 0; f2 < 4; ++f2)
            vf0[ks][f2] = *reinterpret_cast<const bf16x8*>(vpb + ks * 2048 + f2 * 512);

    // ---- normalize -> P tiles (bf16, frag-order swizzled): P0 @ 0, P1 @ 8192
#pragma unroll
    for (int f = 0; f < 16; ++f) {
        f32x4 v0 = acc0[f], v1 = acc1[f];
#pragma unroll
        for (int r = 0; r < 4; ++r) { v0[r] *= invl0; v1[r] *= invl1; }
        bf16x4 p0 = { (bf16_t)v0[0], (bf16_t)v0[1], (bf16_t)v0[2], (bf16_t)v0[3] };
        bf16x4 p1 = { (bf16_t)v1[0], (bf16_t)v1[1], (bf16_t)v1[2], (bf16_t)v1[3] };
        const int ro = lr * 512 + ((f * 32 + lg * 8) ^ myswz);
        *reinterpret_cast<bf16x4*>(tw + ro) = p0;
        *reinterpret_cast<bf16x4*>(tw + 8192 + ro) = p1;
    }

    // ---- attn stores from P tiles: linear LDS b64 read -> cvt f32 -> permuted
    //      global col cc = (lane*4)^((i&7)*8); footprint 1KB contiguous per instr
    {
        float* obase = attn + ((size_t)bh << 20) + (size_t)m0 * 1024 + c0;
#pragma unroll
        for (int i = 0; i < 16; ++i) {
            const int cc = (lane * 4) ^ ((i & 7) * 8);
            bf16x4 q0 = *reinterpret_cast<const bf16x4*>(tw + i * 512 + lane * 8);
            bf16x4 q1 = *reinterpret_cast<const bf16x4*>(tw + 8192 + i * 512 + lane * 8);
            f32x4 w0 = { (float)q0[0], (float)q0[1], (float)q0[2], (float)q0[3] };
            f32x4 w1 = { (float)q1[0], (float)q1[1], (float)q1[2], (float)q1[3] };
            *reinterpret_cast<f32x4*>(obase + (size_t)i * 1024 + cc) = w0;
            *reinterpret_cast<f32x4*>(obase + (size_t)(16 + i) * 1024 + cc) = w1;
        }
    }

    // ---- PV for both tiles; V loaded once (batch 1 issued over batch-0 MFMAs)
    f32x4 cacc0[4], cacc1[4];
#pragma unroll
    for (int f2 = 0; f2 < 4; ++f2) {
        cacc0[f2] = (f32x4){0.f, 0.f, 0.f, 0.f};
        cacc1[f2] = (f32x4){0.f, 0.f, 0.f, 0.f};
    }
    bf16x8 vf1[4][4];
#pragma unroll
    for (int ks = 0; ks < 4; ++ks)
#pragma unroll
        for (int f2 = 0; f2 < 4; ++f2)
            vf1[ks][f2] = *reinterpret_cast<const bf16x8*>(vpb + (4 + ks) * 2048 + f2 * 512);

#pragma unroll
    for (int ks = 0; ks < 4; ++ks) {
        const int po = lr * 512 + ((ks * 64 + lg * 16) ^ myswz);
        bf16x8 pa0 = *reinterpret_cast<const bf16x8*>(tw + po);
        bf16x8 pa1 = *reinterpret_cast<const bf16x8*>(tw + 8192 + po);
#pragma unroll
        for (int f2 = 0; f2 < 4; ++f2) {
            cacc0[f2] = MFMA16(pa0, vf0[ks][f2], cacc0[f2]);
            cacc1[f2] = MFMA16(pa1, vf0[ks][f2], cacc1[f2]);
        }
    }
#pragma unroll
    for (int ks = 4; ks < 8; ++ks) {
        const int po = lr * 512 + ((ks * 64 + lg * 16) ^ myswz);
        bf16x8 pa0 = *reinterpret_cast<const bf16x8*>(tw + po);
        bf16x8 pa1 = *reinterpret_cast<const bf16x8*>(tw + 8192 + po);
#pragma unroll
        for (int f2 = 0; f2 < 4; ++f2) {
            cacc0[f2] = MFMA16(pa0, vf1[ks - 4][f2], cacc0[f2]);
            cacc1[f2] = MFMA16(pa1, vf1[ks - 4][f2], cacc1[f2]);
        }
    }

    // ---- cross-wave ctx reduce: cred[2][16][64] f32 in own region (P dead)
    {
        float* credw = reinterpret_cast<float*>(tw);
#pragma unroll
        for (int f2 = 0; f2 < 4; ++f2)
#pragma unroll
            for (int r = 0; r < 4; ++r) {
                credw[(lg * 4 + r) * 64 + f2 * 16 + lr] = cacc0[f2][r];
                credw[1024 + (lg * 4 + r) * 64 + f2 * 16 + lr] = cacc1[f2][r];
            }
    }
    __syncthreads();
    const int row_l = wave * 4 + lg;
    const int dk0 = lr * 4;
#pragma unroll
    for (int t = 0; t < 2; ++t) {
        f32x4 s0 = *reinterpret_cast<const f32x4*>(
            reinterpret_cast<const float*>(&wlds4[0][0]) + t * 1024 + row_l * 64 + dk0);
        f32x4 s1 = *reinterpret_cast<const f32x4*>(
            reinterpret_cast<const float*>(&wlds4[1][0]) + t * 1024 + row_l * 64 + dk0);
        f32x4 s2 = *reinterpret_cast<const f32x4*>(
            reinterpret_cast<const float*>(&wlds4[2][0]) + t * 1024 + row_l * 64 + dk0);
        f32x4 s3 = *reinterpret_cast<const f32x4*>(
            reinterpret_cast<const float*>(&wlds4[3][0]) + t * 1024 + row_l * 64 + dk0);
        f32x4 st = (s0 + s1) + (s2 + s3);
        bf16x4 o4 = { (bf16_t)st[0], (bf16_t)st[1], (bf16_t)st[2], (bf16_t)st[3] };
        *reinterpret_cast<bf16x4*>(
            &ctxb[(size_t)(b * 1024 + m0 + t * 16 + row_l) * 1024 + h * 64 + dk0]) = o4;
    }
}

// ---------------------------------------------------------------------- launcher
extern "C" void kernel_launch(void* const* d_in, const int* in_sizes, int n_in,
                              void* d_out, int out_size, void* d_ws, size_t ws_size,
                              hipStream_t stream) {
    const float* x    = (const float*)d_in[0];
    const float* bias = (const float*)d_in[1];
    const float* Wq   = (const float*)d_in[2];
    const float* Wk   = (const float*)d_in[3];
    const float* Wv   = (const float*)d_in[4];
    const float* Wo   = (const float*)d_in[5];
    float* out  = (float*)d_out;
    float* attn = out + (size_t)4 * 1024 * 1024;

    char* ws = (char*)d_ws;
    bf16_t* xb   = (bf16_t*)(ws);                      //  8 MB [4096,1024]
    bf16_t* wT   = (bf16_t*)(ws + ((size_t)8 << 20));  //  8 MB 4x [1024,1024] transposed
    bf16_t* qhp  = (bf16_t*)(ws + ((size_t)16 << 20)); //  8 MB Q/8 packed half-planes
    bf16_t* khp  = (bf16_t*)(ws + ((size_t)24 << 20)); //  8 MB K packed half-planes
    bf16_t* vp   = (bf16_t*)(ws + ((size_t)32 << 20)); //  8 MB V packed k-tiles
    bf16_t* ctxb = (bf16_t*)(ws + ((size_t)40 << 20)); //  8 MB ctx [B,S,D]
    bf16_t* woT = wT + ((size_t)3 << 20);

    cast_f32_bf16<<<dim3(4096), dim3(256), 0, stream>>>(x, xb, 1024 * 1024);
    transpose_cast_w<<<dim3(32, 32, 4), dim3(32, 32), 0, stream>>>(Wq, Wk, Wv, Wo, wT);

    gemm_qkv<<<dim3(32, 8, 3), dim3(256), 0, stream>>>(xb, wT, qhp, khp, vp);

    fused_attn<<<dim3(2048), dim3(256), 0, stream>>>(qhp, khp, vp, bias, attn, ctxb);

    gemm_out<<<dim3(32, 8), dim3(256), 0, stream>>>(ctxb, woT, out);
}

// Round 12
// 175.207 us; speedup vs baseline: 1.9670x; 1.0319x over previous
//
#include <hip/hip_runtime.h>
#include <hip/hip_bf16.h>

// MHA forward: B=4, S=1024, D=1024, H=16, DK=64
// outputs: out [4,1024,1024] f32, attn [4,16,1024,1024] f32 (concat in d_out)
//
// Packed operand layouts for the fused kernel (all bf16):
//   qhp/khp: [bh][half=dk/32][s][32]   -> frag loads 1KB contiguous
//   vp:      [bh][kb=s/32][dk][32]     -> PV frag loads 1KB contiguous

typedef __bf16 bf16_t;
typedef __bf16 bf16x4 __attribute__((ext_vector_type(4)));
typedef __bf16 bf16x8 __attribute__((ext_vector_type(8)));
typedef float f32x4 __attribute__((ext_vector_type(4)));

#define MFMA16(a, b, c) __builtin_amdgcn_mfma_f32_16x16x32_bf16(a, b, c, 0, 0, 0)

// ---------------------------------------------------------------- cast x -> bf16
__global__ __launch_bounds__(256) void cast_f32_bf16(const float* __restrict__ in,
                                                     bf16_t* __restrict__ out, int n4) {
    int i = blockIdx.x * blockDim.x + threadIdx.x;
    if (i >= n4) return;
    float4 v = reinterpret_cast<const float4*>(in)[i];
    bf16x4 o = { (bf16_t)v.x, (bf16_t)v.y, (bf16_t)v.z, (bf16_t)v.w };
    reinterpret_cast<bf16x4*>(out)[i] = o;
}

// ------------------------------------------- transpose + cast the 4 weight matrices
__global__ __launch_bounds__(1024) void transpose_cast_w(const float* __restrict__ w0,
                                                         const float* __restrict__ w1,
                                                         const float* __restrict__ w2,
                                                         const float* __restrict__ w3,
                                                         bf16_t* __restrict__ wt) {
    __shared__ float tile[32][33];
    const float* src = (blockIdx.z == 0) ? w0 : (blockIdx.z == 1) ? w1
                     : (blockIdx.z == 2) ? w2 : w3;
    bf16_t* dst = wt + (size_t)blockIdx.z * 1024 * 1024;
    int r0 = blockIdx.y * 32, c0 = blockIdx.x * 32;
    tile[threadIdx.y][threadIdx.x] = src[(size_t)(r0 + threadIdx.y) * 1024 + c0 + threadIdx.x];
    __syncthreads();
    dst[(size_t)(c0 + threadIdx.y) * 1024 + r0 + threadIdx.x] = (bf16_t)tile[threadIdx.x][threadIdx.y];
}

// ------------------------------------------------- GEMM core (128x128 tile, BK=64)
// block = 256 threads = 4 waves (2x2), each wave 64x64 output (4x4 frags).
// 16 K-steps of 64 (half the barriers of BK=32). Staging: thread t, chunk i:
// g = i*256+t -> row g>>3, slot g&7; per wave-instruction lanes cover 8 rows x
// 128B contiguous (line-optimal). LDS swizzle slot' = slot ^ (row&7) (8 slots,
// read side identical) -> b128 reads at the 8-cycle floor.
#define GEMM_BODY(A, BT)                                                                 \
    __shared__ bf16_t As[128 * 64];                                                      \
    __shared__ bf16_t Bs[128 * 64];                                                      \
    const int tid = threadIdx.x;                                                         \
    const int lane = tid & 63, wave = tid >> 6;                                          \
    const int lr = lane & 15, lg = lane >> 4;                                            \
    const int m_base = blockIdx.x * 128, n_base = blockIdx.y * 128;                      \
    const int wm = (wave >> 1) * 64, wn = (wave & 1) * 64;                               \
    int soff_[4];                                                                        \
    const bf16_t* aptr_[4];                                                              \
    const bf16_t* bptr_[4];                                                              \
    _Pragma("unroll") for (int i = 0; i < 4; ++i) {                                      \
        const int g = i * 256 + tid;                                                     \
        const int r = g >> 3, s = g & 7;                                                 \
        soff_[i] = r * 64 + ((s ^ (r & 7)) * 8);                                         \
        aptr_[i] = (A) + (size_t)(m_base + r) * 1024 + s * 8;                            \
        bptr_[i] = (BT) + (size_t)(n_base + r) * 1024 + s * 8;                           \
    }                                                                                    \
    bf16x8 ra_[4], rb_[4];                                                               \
    _Pragma("unroll") for (int i = 0; i < 4; ++i) {                                      \
        ra_[i] = *reinterpret_cast<const bf16x8*>(aptr_[i]);                             \
        rb_[i] = *reinterpret_cast<const bf16x8*>(bptr_[i]);                             \
    }                                                                                    \
    f32x4 acc[4][4] = {};                                                                \
    for (int kb = 64; kb <= 1024; kb += 64) {                                            \
        __syncthreads();                                                                 \
        _Pragma("unroll") for (int i = 0; i < 4; ++i) {                                  \
            *reinterpret_cast<bf16x8*>(&As[soff_[i]]) = ra_[i];                          \
            *reinterpret_cast<bf16x8*>(&Bs[soff_[i]]) = rb_[i];                          \
        }                                                                                \
        if (kb < 1024) {                                                                 \
            _Pragma("unroll") for (int i = 0; i < 4; ++i) {                              \
                ra_[i] = *reinterpret_cast<const bf16x8*>(aptr_[i] + kb);                \
                rb_[i] = *reinterpret_cast<const bf16x8*>(bptr_[i] + kb);                \
            }                                                                            \
        }                                                                                \
        __syncthreads();                                                                 \
        _Pragma("unroll") for (int h = 0; h < 2; ++h) {                                  \
            bf16x8 af[4], bfr[4];                                                        \
            _Pragma("unroll") for (int i = 0; i < 4; ++i) {                              \
                const int row = wm + i * 16 + lr;                                        \
                af[i] = *reinterpret_cast<const bf16x8*>(                                \
                    &As[row * 64 + (((h * 4 + lg) ^ (row & 7)) * 8)]);                   \
            }                                                                            \
            _Pragma("unroll") for (int j = 0; j < 4; ++j) {                              \
                const int row = wn + j * 16 + lr;                                        \
                bfr[j] = *reinterpret_cast<const bf16x8*>(                               \
                    &Bs[row * 64 + (((h * 4 + lg) ^ (row & 7)) * 8)]);                   \
            }                                                                            \
            _Pragma("unroll") for (int i = 0; i < 4; ++i)                                \
                _Pragma("unroll") for (int j = 0; j < 4; ++j)                            \
                    acc[i][j] = MFMA16(af[i], bfr[j], acc[i][j]);                        \
        }                                                                                \
    }

// ---------------------------------------------------- QKV projections, one launch
// blockIdx.z: 0 = Q -> qhp (x0.125), 1 = K -> khp, 2 = V -> vp
__global__ __launch_bounds__(256, 3) void gemm_qkv(const bf16_t* __restrict__ A,
                                                   const bf16_t* __restrict__ wT,
                                                   bf16_t* __restrict__ qhp,
                                                   bf16_t* __restrict__ khp,
                                                   bf16_t* __restrict__ vp) {
    const int z = blockIdx.z;
    const bf16_t* BT = wT + ((size_t)z << 20);
    GEMM_BODY(A, BT)
    bf16_t* dst = (z == 0) ? qhp : (z == 1) ? khp : vp;
    const float scale = (z == 0) ? 0.125f : 1.0f;
#pragma unroll
    for (int i = 0; i < 4; ++i)
#pragma unroll
        for (int j = 0; j < 4; ++j)
#pragma unroll
            for (int r = 0; r < 4; ++r) {
                const int row = m_base + wm + i * 16 + lg * 4 + r;
                const int col = n_base + wn + j * 16 + lr;
                const float v = acc[i][j][r] * scale;
                const int b = row >> 10, s = row & 1023;
                const int h = col >> 6, d = col & 63;
                const size_t bh16 = (size_t)(b * 16 + h) << 16;
                if (z == 2)   // vp[bh][s/32][d][s%32]
                    dst[bh16 + ((s >> 5) << 11) + d * 32 + (s & 31)] = (bf16_t)v;
                else          // qhp/khp[bh][d/32][s][d%32]
                    dst[bh16 + ((d >> 5) << 15) + s * 32 + (d & 31)] = (bf16_t)v;
            }
}

// ------------------------------------------------------------- output projection
__global__ __launch_bounds__(256, 3) void gemm_out(const bf16_t* __restrict__ A,
                                                   const bf16_t* __restrict__ BT,
                                                   float* __restrict__ out) {
    GEMM_BODY(A, BT)
#pragma unroll
    for (int i = 0; i < 4; ++i)
#pragma unroll
        for (int j = 0; j < 4; ++j)
#pragma unroll
            for (int r = 0; r < 4; ++r) {
                const int row = m_base + wm + i * 16 + lg * 4 + r;
                const int col = n_base + wn + j * 16 + lr;
                out[(size_t)row * 1024 + col] = acc[i][j][r];
            }
}

// --------------------------------------- fused scores+bias+softmax+attn-write+PV
// (unchanged from round 11 — 2-q-tile, K/V loaded once, segment-coalesced I/O)
__global__ __launch_bounds__(256, 2) void fused_attn(const bf16_t* __restrict__ qhp,
                                                     const bf16_t* __restrict__ khp,
                                                     const bf16_t* __restrict__ vp,
                                                     const float* __restrict__ bias,
                                                     float* __restrict__ attn,
                                                     bf16_t* __restrict__ ctxb) {
    __shared__ f32x4 wlds4[4][1024];        // 65536 B: per-wave 16KB region
    __shared__ float smaxp[128];            // [tile][wave*16+q]
    __shared__ float ssump[128];
    const int lane = threadIdx.x & 63;
    const int wave = threadIdx.x >> 6;
    const int lr = lane & 15, lg = lane >> 4;

    // decode 2048 blocks: g&7 = xcd slot; per-xcd: b fastest, qt, then h-ext
    const int g = blockIdx.x;
    const int j = g >> 3;                   // 0..255
    const int h = (g & 7) + 8 * (j >> 7);   // 0..15
    const int qt = (j >> 2) & 31;           // 32-row q-tile
    const int b = j & 3;
    const int bh = b * 16 + h;
    const int m0 = qt * 32;                 // tile0: m0..+15, tile1: m0+16..+31

    // Q B-frags for both tiles
    const bf16_t* qbase = qhp + ((size_t)bh << 16);
    const bf16x8 aqA0 = *reinterpret_cast<const bf16x8*>(qbase + (m0 + lr) * 32 + lg * 8);
    const bf16x8 aqA1 = *reinterpret_cast<const bf16x8*>(qbase + 32768 + (m0 + lr) * 32 + lg * 8);
    const bf16x8 aqB0 = *reinterpret_cast<const bf16x8*>(qbase + (m0 + 16 + lr) * 32 + lg * 8);
    const bf16x8 aqB1 = *reinterpret_cast<const bf16x8*>(qbase + 32768 + (m0 + 16 + lr) * 32 + lg * 8);

    const int c0 = wave * 256;              // this wave's k-col slice
    const bf16_t* kp0 = khp + ((size_t)bh << 16) + (size_t)(c0 + lr) * 32 + lg * 8;

    char* tw = reinterpret_cast<char*>(&wlds4[wave][0]);
    const int myswz = (lr & 7) << 4;

    // ---- bias tile0 -> LDS (permuted global col, linear LDS dest = swizzled tile)
    const float* bb0 = bias + ((size_t)h << 20) + (size_t)m0 * 1024 + c0;
#pragma unroll
    for (int i = 0; i < 16; ++i) {
        const int co = (lane * 4) ^ ((i & 7) * 4);
        f32x4 bv = *reinterpret_cast<const f32x4*>(bb0 + (size_t)i * 1024 + co);
        *reinterpret_cast<f32x4*>(tw + i * 1024 + lane * 16) = bv;
    }
    f32x4 acc0[16];
#pragma unroll
    for (int f = 0; f < 16; ++f)
        acc0[f] = *reinterpret_cast<const f32x4*>(tw + lr * 1024 + ((f * 64 + lg * 16) ^ myswz));

    // ---- bias tile1 -> LDS (reuse region), init acc1
    const float* bb1 = bb0 + 16 * 1024;
#pragma unroll
    for (int i = 0; i < 16; ++i) {
        const int co = (lane * 4) ^ ((i & 7) * 4);
        f32x4 bv = *reinterpret_cast<const f32x4*>(bb1 + (size_t)i * 1024 + co);
        *reinterpret_cast<f32x4*>(tw + i * 1024 + lane * 16) = bv;
    }
    f32x4 acc1[16];
#pragma unroll
    for (int f = 0; f < 16; ++f)
        acc1[f] = *reinterpret_cast<const f32x4*>(tw + lr * 1024 + ((f * 64 + lg * 16) ^ myswz));

    // ---- QK^T (swapped) for both tiles; K in 4 transient batches of 8 frags
#pragma unroll
    for (int half = 0; half < 2; ++half) {
        const bf16x8 aqA = half ? aqA1 : aqA0;
        const bf16x8 aqB = half ? aqB1 : aqB0;
#pragma unroll
        for (int bt = 0; bt < 2; ++bt) {
            bf16x8 kf[8];
#pragma unroll
            for (int u = 0; u < 8; ++u)
                kf[u] = *reinterpret_cast<const bf16x8*>(
                    kp0 + half * 32768 + (bt * 8 + u) * 512);
#pragma unroll
            for (int u = 0; u < 8; ++u) {
                acc0[bt * 8 + u] = MFMA16(kf[u], aqA, acc0[bt * 8 + u]);
                acc1[bt * 8 + u] = MFMA16(kf[u], aqB, acc1[bt * 8 + u]);
            }
        }
    }

    // ---- row max (both tiles): in-lane over 64 + shuffle xor16/32 + LDS
    f32x4 m40 = acc0[0], m41 = acc1[0];
#pragma unroll
    for (int f = 1; f < 16; ++f) {
#pragma unroll
        for (int r = 0; r < 4; ++r) {
            m40[r] = fmaxf(m40[r], acc0[f][r]);
            m41[r] = fmaxf(m41[r], acc1[f][r]);
        }
    }
    float mx0 = fmaxf(fmaxf(m40[0], m40[1]), fmaxf(m40[2], m40[3]));
    float mx1 = fmaxf(fmaxf(m41[0], m41[1]), fmaxf(m41[2], m41[3]));
    mx0 = fmaxf(mx0, __shfl_xor(mx0, 16));
    mx0 = fmaxf(mx0, __shfl_xor(mx0, 32));
    mx1 = fmaxf(mx1, __shfl_xor(mx1, 16));
    mx1 = fmaxf(mx1, __shfl_xor(mx1, 32));
    if (lane < 16) {
        smaxp[wave * 16 + lr] = mx0;
        smaxp[64 + wave * 16 + lr] = mx1;
    }
    __syncthreads();
    const float gm0 = fmaxf(fmaxf(smaxp[lr], smaxp[16 + lr]),
                            fmaxf(smaxp[32 + lr], smaxp[48 + lr]));
    const float gm1 = fmaxf(fmaxf(smaxp[64 + lr], smaxp[80 + lr]),
                            fmaxf(smaxp[96 + lr], smaxp[112 + lr]));

    // ---- exp once + row sums (both tiles)
    f32x4 s40 = {0.f, 0.f, 0.f, 0.f}, s41 = {0.f, 0.f, 0.f, 0.f};
#pragma unroll
    for (int f = 0; f < 16; ++f) {
#pragma unroll
        for (int r = 0; r < 4; ++r) {
            const float e0 = __expf(acc0[f][r] - gm0);
            const float e1 = __expf(acc1[f][r] - gm1);
            acc0[f][r] = e0;
            acc1[f][r] = e1;
            s40[r] += e0;
            s41[r] += e1;
        }
    }
    float sm0 = (s40[0] + s40[1]) + (s40[2] + s40[3]);
    float sm1 = (s41[0] + s41[1]) + (s41[2] + s41[3]);
    sm0 += __shfl_xor(sm0, 16);
    sm0 += __shfl_xor(sm0, 32);
    sm1 += __shfl_xor(sm1, 16);
    sm1 += __shfl_xor(sm1, 32);
    if (lane < 16) {
        ssump[wave * 16 + lr] = sm0;
        ssump[64 + wave * 16 + lr] = sm1;
    }
    __syncthreads();
    const float invl0 = 1.0f / (ssump[lr] + ssump[16 + lr] + ssump[32 + lr] + ssump[48 + lr]);
    const float invl1 = 1.0f / (ssump[64 + lr] + ssump[80 + lr] + ssump[96 + lr] + ssump[112 + lr]);

    // ---- issue V batch 0 early (shared by both tiles' PV)
    const bf16_t* vpb = vp + ((size_t)bh << 16) + (size_t)(wave * 8) * 2048 + lr * 32 + lg * 8;
    bf16x8 vf0[4][4];
#pragma unroll
    for (int ks = 0; ks < 4; ++ks)
#pragma unroll
        for (int f2 = 0; f2 < 4; ++f2)
            vf0[ks][f2] = *reinterpret_cast<const bf16x8*>(vpb + ks * 2048 + f2 * 512);

    // ---- normalize -> P tiles (bf16, frag-order swizzled): P0 @ 0, P1 @ 8192
#pragma unroll
    for (int f = 0; f < 16; ++f) {
        f32x4 v0 = acc0[f], v1 = acc1[f];
#pragma unroll
        for (int r = 0; r < 4; ++r) { v0[r] *= invl0; v1[r] *= invl1; }
        bf16x4 p0 = { (bf16_t)v0[0], (bf16_t)v0[1], (bf16_t)v0[2], (bf16_t)v0[3] };
        bf16x4 p1 = { (bf16_t)v1[0], (bf16_t)v1[1], (bf16_t)v1[2], (bf16_t)v1[3] };
        const int ro = lr * 512 + ((f * 32 + lg * 8) ^ myswz);
        *reinterpret_cast<bf16x4*>(tw + ro) = p0;
        *reinterpret_cast<bf16x4*>(tw + 8192 + ro) = p1;
    }

    // ---- attn stores from P tiles: linear LDS b64 read -> cvt f32 -> permuted
    //      global col cc = (lane*4)^((i&7)*8); footprint 1KB contiguous per instr
    {
        float* obase = attn + ((size_t)bh << 20) + (size_t)m0 * 1024 + c0;
#pragma unroll
        for (int i = 0; i < 16; ++i) {
            const int cc = (lane * 4) ^ ((i & 7) * 8);
            bf16x4 q0 = *reinterpret_cast<const bf16x4*>(tw + i * 512 + lane * 8);
            bf16x4 q1 = *reinterpret_cast<const bf16x4*>(tw + 8192 + i * 512 + lane * 8);
            f32x4 w0 = { (float)q0[0], (float)q0[1], (float)q0[2], (float)q0[3] };
            f32x4 w1 = { (float)q1[0], (float)q1[1], (float)q1[2], (float)q1[3] };
            *reinterpret_cast<f32x4*>(obase + (size_t)i * 1024 + cc) = w0;
            *reinterpret_cast<f32x4*>(obase + (size_t)(16 + i) * 1024 + cc) = w1;
        }
    }

    // ---- PV for both tiles; V loaded once (batch 1 issued over batch-0 MFMAs)
    f32x4 cacc0[4], cacc1[4];
#pragma unroll
    for (int f2 = 0; f2 < 4; ++f2) {
        cacc0[f2] = (f32x4){0.f, 0.f, 0.f, 0.f};
        cacc1[f2] = (f32x4){0.f, 0.f, 0.f, 0.f};
    }
    bf16x8 vf1[4][4];
#pragma unroll
    for (int ks = 0; ks < 4; ++ks)
#pragma unroll
        for (int f2 = 0; f2 < 4; ++f2)
            vf1[ks][f2] = *reinterpret_cast<const bf16x8*>(vpb + (4 + ks) * 2048 + f2 * 512);

#pragma unroll
    for (int ks = 0; ks < 4; ++ks) {
        const int po = lr * 512 + ((ks * 64 + lg * 16) ^ myswz);
        bf16x8 pa0 = *reinterpret_cast<const bf16x8*>(tw + po);
        bf16x8 pa1 = *reinterpret_cast<const bf16x8*>(tw + 8192 + po);
#pragma unroll
        for (int f2 = 0; f2 < 4; ++f2) {
            cacc0[f2] = MFMA16(pa0, vf0[ks][f2], cacc0[f2]);
            cacc1[f2] = MFMA16(pa1, vf0[ks][f2], cacc1[f2]);
        }
    }
#pragma unroll
    for (int ks = 4; ks < 8; ++ks) {
        const int po = lr * 512 + ((ks * 64 + lg * 16) ^ myswz);
        bf16x8 pa0 = *reinterpret_cast<const bf16x8*>(tw + po);
        bf16x8 pa1 = *reinterpret_cast<const bf16x8*>(tw + 8192 + po);
#pragma unroll
        for (int f2 = 0; f2 < 4; ++f2) {
            cacc0[f2] = MFMA16(pa0, vf1[ks - 4][f2], cacc0[f2]);
            cacc1[f2] = MFMA16(pa1, vf1[ks - 4][f2], cacc1[f2]);
        }
    }

    // ---- cross-wave ctx reduce: cred[2][16][64] f32 in own region (P dead)
    {
        float* credw = reinterpret_cast<float*>(tw);
#pragma unroll
        for (int f2 = 0; f2 < 4; ++f2)
#pragma unroll
            for (int r = 0; r < 4; ++r) {
                credw[(lg * 4 + r) * 64 + f2 * 16 + lr] = cacc0[f2][r];
                credw[1024 + (lg * 4 + r) * 64 + f2 * 16 + lr] = cacc1[f2][r];
            }
    }
    __syncthreads();
    const int row_l = wave * 4 + lg;
    const int dk0 = lr * 4;
#pragma unroll
    for (int t = 0; t < 2; ++t) {
        f32x4 s0 = *reinterpret_cast<const f32x4*>(
            reinterpret_cast<const float*>(&wlds4[0][0]) + t * 1024 + row_l * 64 + dk0);
        f32x4 s1 = *reinterpret_cast<const f32x4*>(
            reinterpret_cast<const float*>(&wlds4[1][0]) + t * 1024 + row_l * 64 + dk0);
        f32x4 s2 = *reinterpret_cast<const f32x4*>(
            reinterpret_cast<const float*>(&wlds4[2][0]) + t * 1024 + row_l * 64 + dk0);
        f32x4 s3 = *reinterpret_cast<const f32x4*>(
            reinterpret_cast<const float*>(&wlds4[3][0]) + t * 1024 + row_l * 64 + dk0);
        f32x4 st = (s0 + s1) + (s2 + s3);
        bf16x4 o4 = { (bf16_t)st[0], (bf16_t)st[1], (bf16_t)st[2], (bf16_t)st[3] };
        *reinterpret_cast<bf16x4*>(
            &ctxb[(size_t)(b * 1024 + m0 + t * 16 + row_l) * 1024 + h * 64 + dk0]) = o4;
    }
}

// ---------------------------------------------------------------------- launcher
extern "C" void kernel_launch(void* const* d_in, const int* in_sizes, int n_in,
                              void* d_out, int out_size, void* d_ws, size_t ws_size,
                              hipStream_t stream) {
    const float* x    = (const float*)d_in[0];
    const float* bias = (const float*)d_in[1];
    const float* Wq   = (const float*)d_in[2];
    const float* Wk   = (const float*)d_in[3];
    const float* Wv   = (const float*)d_in[4];
    const float* Wo   = (const float*)d_in[5];
    float* out  = (float*)d_out;
    float* attn = out + (size_t)4 * 1024 * 1024;

    char* ws = (char*)d_ws;
    bf16_t* xb   = (bf16_t*)(ws);                      //  8 MB [4096,1024]
    bf16_t* wT   = (bf16_t*)(ws + ((size_t)8 << 20));  //  8 MB 4x [1024,1024] transposed
    bf16_t* qhp  = (bf16_t*)(ws + ((size_t)16 << 20)); //  8 MB Q/8 packed half-planes
    bf16_t* khp  = (bf16_t*)(ws + ((size_t)24 << 20)); //  8 MB K packed half-planes
    bf16_t* vp   = (bf16_t*)(ws + ((size_t)32 << 20)); //  8 MB V packed k-tiles
    bf16_t* ctxb = (bf16_t*)(ws + ((size_t)40 << 20)); //  8 MB ctx [B,S,D]
    bf16_t* woT = wT + ((size_t)3 << 20);

    cast_f32_bf16<<<dim3(4096), dim3(256), 0, stream>>>(x, xb, 1024 * 1024);
    transpose_cast_w<<<dim3(32, 32, 4), dim3(32, 32), 0, stream>>>(Wq, Wk, Wv, Wo, wT);

    gemm_qkv<<<dim3(32, 8, 3), dim3(256), 0, stream>>>(xb, wT, qhp, khp, vp);

    fused_attn<<<dim3(2048), dim3(256), 0, stream>>>(qhp, khp, vp, bias, attn, ctxb);

    gemm_out<<<dim3(32, 8), dim3(256), 0, stream>>>(ctxb, woT, out);
}